// Round 3
// baseline (1569.496 us; speedup 1.0000x reference)
//
#include <hip/hip_runtime.h>
#include <cstdint>

#define DEV static __device__ __forceinline__

typedef unsigned short u16;
typedef __bf16 bf16x8 __attribute__((ext_vector_type(8)));
typedef float f32x4 __attribute__((ext_vector_type(4)));
typedef unsigned short u16x4 __attribute__((ext_vector_type(4)));

constexpr int V = 32000, D = 1024, H = 16, L = 4, F = 4096, T = 1024, B = 2;
constexpr int HD = 64;

DEV u16 f2bf(float f) {
    union { float f; uint32_t i; } c; c.f = f;
    uint32_t x = c.i;
    return (u16)((x + 0x7fffu + ((x >> 16) & 1u)) >> 16);
}
DEV bf16x8 ld8(const u16* p) { return *reinterpret_cast<const bf16x8*>(p); }

DEV void gl16(const void* g, void* l) {
    __builtin_amdgcn_global_load_lds((const __attribute__((address_space(1))) void*)g,
                                     (__attribute__((address_space(3))) void*)l, 16, 0, 0);
}

// ---------------- embedding: x = emb[tok] + pe (all f32) ----------------
__global__ __launch_bounds__(256) void k_embed(const int* __restrict__ tok,
        const float* __restrict__ emb, const float* __restrict__ pe, float* __restrict__ x) {
    int i = blockIdx.x;              // b*T + t
    int t = i & (T - 1);
    int v = tok[i];
    const f32x4* er = (const f32x4*)(emb + (size_t)v * D);
    const f32x4* pr = (const f32x4*)(pe + (size_t)t * D);
    f32x4* xr = (f32x4*)(x + (size_t)i * D);
    int tid = threadIdx.x;
    xr[tid] = er[tid] + pr[tid];
}

// ---------------- elementwise cast f32 -> bf16 ----------------
__global__ __launch_bounds__(256) void k_cast(const float* __restrict__ src,
        u16* __restrict__ dst) {
    int i = (blockIdx.x * 256 + threadIdx.x) * 4;
    f32x4 v = *(const f32x4*)(src + i);
    u16x4 o;
#pragma unroll
    for (int j = 0; j < 4; j++) o[j] = f2bf(v[j]);
    *(u16x4*)(dst + i) = o;
}

// ---------------- layernorm: f32 in -> bf16 out ----------------
__global__ __launch_bounds__(256) void k_lnorm(const float* __restrict__ x,
        const float* __restrict__ g, const float* __restrict__ b, u16* __restrict__ out) {
    int row = blockIdx.x;
    int tid = threadIdx.x;
    f32x4 v = ((const f32x4*)(x + (size_t)row * D))[tid];
    float s = v[0] + v[1] + v[2] + v[3];
    float s2 = v[0]*v[0] + v[1]*v[1] + v[2]*v[2] + v[3]*v[3];
#pragma unroll
    for (int m = 1; m < 64; m <<= 1) { s += __shfl_xor(s, m); s2 += __shfl_xor(s2, m); }
    __shared__ float ps[4], ps2[4];
    int wave = tid >> 6;
    if ((tid & 63) == 0) { ps[wave] = s; ps2[wave] = s2; }
    __syncthreads();
    s = ps[0] + ps[1] + ps[2] + ps[3];
    s2 = ps2[0] + ps2[1] + ps2[2] + ps2[3];
    float mean = s * (1.f / D);
    float var = s2 * (1.f / D) - mean * mean;
    float r = rsqrtf(var + 1e-5f);
    f32x4 gg = ((const f32x4*)g)[tid];
    f32x4 bb = ((const f32x4*)b)[tid];
    u16x4 o;
#pragma unroll
    for (int j = 0; j < 4; j++) o[j] = f2bf((v[j] - mean) * r * gg[j] + bb[j]);
    ((u16x4*)(out + (size_t)row * D))[tid] = o;
}

// ---------------- transpose + cast: dst[C,R](bf16) = src[R,C](f32)^T ----------------
__global__ __launch_bounds__(256) void k_castT(const float* __restrict__ src,
        u16* __restrict__ dst, int R, int C) {
    __shared__ u16 tl[32][33];
    int c0 = blockIdx.x * 32, r0 = blockIdx.y * 32;
    int x = threadIdx.x & 31, y = threadIdx.x >> 5;
#pragma unroll
    for (int i = 0; i < 4; i++)
        tl[y + i * 8][x] = f2bf(src[(size_t)(r0 + y + i * 8) * C + c0 + x]);
    __syncthreads();
#pragma unroll
    for (int i = 0; i < 4; i++)
        dst[(size_t)(c0 + y + i * 8) * R + r0 + x] = tl[x][y + i * 8];
}

// ---------------- V^T extraction: vT[b,h,hd,t] = qkv_v[b,t,h,hd] (bf16) ----------------
__global__ __launch_bounds__(256) void k_vtrans(const u16* __restrict__ qkv, u16* __restrict__ vT) {
    int bh = blockIdx.z; int b = bh >> 4, h = bh & 15;
    int t0 = blockIdx.x * 32, d0 = blockIdx.y * 32;
    __shared__ u16 tl[32][33];
    int x = threadIdx.x & 31, y = threadIdx.x >> 5;
#pragma unroll
    for (int i = 0; i < 4; i++)
        tl[y + i * 8][x] = qkv[(size_t)(b * T + t0 + y + i * 8) * (3 * D) + 2 * D + h * HD + d0 + x];
    __syncthreads();
#pragma unroll
    for (int i = 0; i < 4; i++)
        vT[((size_t)bh * HD + d0 + y + i * 8) * T + t0 + x] = tl[x][y + i * 8];
}

// ---------------- GEMM: C[M,N] = A[M,K](bf16) @ Bt[N,K](bf16)^T + bias(f32) ----------------
// EPI: 0 = store bf16, 1 = GELU->bf16, 2 = add into f32 residual, 3 = store f32
template <int EPI>
__global__ __launch_bounds__(256) void k_gemm_bt(
        const u16* __restrict__ A, int lda,
        const u16* __restrict__ Bt, int ldb,
        const float* __restrict__ bias,
        void* __restrict__ Cv, int ldc, int K) {
    __shared__ u16 tA[128 * 32];
    __shared__ u16 tB[128 * 32];
    int m0 = blockIdx.x * 128, n0 = blockIdx.y * 128;
    int tid = threadIdx.x, wave = tid >> 6, lane = tid & 63;
    int llo = lane & 15, lhi = lane >> 4;
    int wr = wave >> 1, wc = wave & 1;
    f32x4 acc[4][4] = {};
    for (int k0 = 0; k0 < K; k0 += 32) {
        for (int c = wave; c < 8; c += 4) {
            int e = (c * 64 + lane) * 8;
            int row = e >> 5, col = e & 31;
            gl16(A  + (size_t)(m0 + row) * lda + k0 + col, &tA[c * 512]);
            gl16(Bt + (size_t)(n0 + row) * ldb + k0 + col, &tB[c * 512]);
        }
        __syncthreads();
        bf16x8 af[4], bfr[4];
#pragma unroll
        for (int mi = 0; mi < 4; mi++) af[mi] = ld8(&tA[(wr * 64 + mi * 16 + llo) * 32 + lhi * 8]);
#pragma unroll
        for (int ni = 0; ni < 4; ni++) bfr[ni] = ld8(&tB[(wc * 64 + ni * 16 + llo) * 32 + lhi * 8]);
#pragma unroll
        for (int mi = 0; mi < 4; mi++)
#pragma unroll
            for (int ni = 0; ni < 4; ni++)
                acc[mi][ni] = __builtin_amdgcn_mfma_f32_16x16x32_bf16(af[mi], bfr[ni], acc[mi][ni], 0, 0, 0);
        __syncthreads();
    }
#pragma unroll
    for (int ni = 0; ni < 4; ni++) {
        int col = n0 + wc * 64 + ni * 16 + llo;
        float bb = bias[col];
#pragma unroll
        for (int mi = 0; mi < 4; mi++) {
#pragma unroll
            for (int r = 0; r < 4; r++) {
                int row = m0 + wr * 64 + mi * 16 + lhi * 4 + r;
                float o = acc[mi][ni][r] + bb;
                if (EPI == 1) o = 0.5f * o * (1.f + erff(o * 0.70710678118f));
                if (EPI == 2) {
                    ((float*)Cv)[(size_t)row * ldc + col] += o;
                } else if (EPI == 3) {
                    ((float*)Cv)[(size_t)row * ldc + col] = o;
                } else {
                    ((u16*)Cv)[(size_t)row * ldc + col] = f2bf(o);
                }
            }
        }
    }
}

// ---------------- fused QK^T + causal softmax -> probs (bf16 ws, f32 d_out opt) ----------------
template <bool WF32>
__global__ __launch_bounds__(256) void k_attn(const u16* __restrict__ qkv,
        float* __restrict__ attn_f32, u16* __restrict__ pb) {
    int bh = blockIdx.y; int b = bh >> 4, h = bh & 15;
    int tid = threadIdx.x, wave = tid >> 6, lane = tid & 63;
    int llo = lane & 15, lhi = lane >> 4;
    int i0 = blockIdx.x * 64 + wave * 16;
    const u16* qb = qkv + (size_t)b * T * (3 * D) + h * HD;
    const u16* kb = qb + D;
    bf16x8 a0 = ld8(qb + (size_t)(i0 + llo) * (3 * D) + lhi * 8);
    bf16x8 a1 = ld8(qb + (size_t)(i0 + llo) * (3 * D) + 32 + lhi * 8);
    float mloc[4], sloc[4];
#pragma unroll
    for (int r = 0; r < 4; r++) { mloc[r] = -1e30f; sloc[r] = 0.f; }
    for (int j0 = 0; j0 <= i0 + 15; j0 += 16) {
        bf16x8 b0 = ld8(kb + (size_t)(j0 + llo) * (3 * D) + lhi * 8);
        bf16x8 b1 = ld8(kb + (size_t)(j0 + llo) * (3 * D) + 32 + lhi * 8);
        f32x4 acc = {};
        acc = __builtin_amdgcn_mfma_f32_16x16x32_bf16(a0, b0, acc, 0, 0, 0);
        acc = __builtin_amdgcn_mfma_f32_16x16x32_bf16(a1, b1, acc, 0, 0, 0);
#pragma unroll
        for (int r = 0; r < 4; r++) {
            int i = i0 + lhi * 4 + r;
            int j = j0 + llo;
            float vv = (j <= i) ? acc[r] * 0.125f : -1e9f;
            float nm = fmaxf(mloc[r], vv);
            sloc[r] = sloc[r] * __expf(mloc[r] - nm) + __expf(vv - nm);
            mloc[r] = nm;
        }
    }
    float Mf[4], Sinv[4];
#pragma unroll
    for (int r = 0; r < 4; r++) {
        float M = mloc[r], S = sloc[r];
#pragma unroll
        for (int m = 1; m < 16; m <<= 1) {
            float Mo = __shfl_xor(M, m), So = __shfl_xor(S, m);
            float nm = fmaxf(M, Mo);
            S = S * __expf(M - nm) + So * __expf(Mo - nm);
            M = nm;
        }
        Mf[r] = M; Sinv[r] = 1.f / S;
    }
    u16* pr = pb + (size_t)bh * T * T;
    float* ar = attn_f32 + (size_t)bh * T * T;
    for (int j0 = 0; j0 < T; j0 += 16) {
        int j = j0 + llo;
        if (j0 <= i0 + 15) {
            bf16x8 b0 = ld8(kb + (size_t)(j0 + llo) * (3 * D) + lhi * 8);
            bf16x8 b1 = ld8(kb + (size_t)(j0 + llo) * (3 * D) + 32 + lhi * 8);
            f32x4 acc = {};
            acc = __builtin_amdgcn_mfma_f32_16x16x32_bf16(a0, b0, acc, 0, 0, 0);
            acc = __builtin_amdgcn_mfma_f32_16x16x32_bf16(a1, b1, acc, 0, 0, 0);
#pragma unroll
            for (int r = 0; r < 4; r++) {
                int i = i0 + lhi * 4 + r;
                float p = (j <= i) ? __expf(acc[r] * 0.125f - Mf[r]) * Sinv[r] : 0.f;
                pr[(size_t)i * T + j] = f2bf(p);
                if (WF32) ar[(size_t)i * T + j] = p;
            }
        } else {
#pragma unroll
            for (int r = 0; r < 4; r++) {
                int i = i0 + lhi * 4 + r;
                pr[(size_t)i * T + j] = 0;
                if (WF32) ar[(size_t)i * T + j] = 0.f;
            }
        }
    }
}

// ---------------- PV: out[b,t,h*64+d] = sum_j P[i,j] * V[j,d] ----------------
__global__ __launch_bounds__(256) void k_pv(const u16* __restrict__ pb,
        const u16* __restrict__ vT, u16* __restrict__ out) {
    int bh = blockIdx.y; int b = bh >> 4, h = bh & 15;
    int tid = threadIdx.x, wave = tid >> 6, lane = tid & 63;
    int llo = lane & 15, lhi = lane >> 4;
    int i0 = blockIdx.x * 64 + wave * 16;
    const u16* pr = pb + (size_t)bh * T * T;
    const u16* vt = vT + (size_t)bh * HD * T;
    f32x4 acc[4] = {};
    int kend = i0 + 16;
    for (int k0 = 0; k0 < kend; k0 += 32) {
        bf16x8 a = ld8(pr + (size_t)(i0 + llo) * T + k0 + lhi * 8);
#pragma unroll
        for (int n = 0; n < 4; n++) {
            bf16x8 bb = ld8(vt + (size_t)(n * 16 + llo) * T + k0 + lhi * 8);
            acc[n] = __builtin_amdgcn_mfma_f32_16x16x32_bf16(a, bb, acc[n], 0, 0, 0);
        }
    }
#pragma unroll
    for (int n = 0; n < 4; n++)
#pragma unroll
        for (int r = 0; r < 4; r++) {
            int i = i0 + lhi * 4 + r, c = n * 16 + llo;
            out[(size_t)(b * T + i) * D + h * HD + c] = f2bf(acc[n][r]);
        }
}

extern "C" void kernel_launch(void* const* d_in, const int* in_sizes, int n_in,
                              void* d_out, int out_size, void* d_ws, size_t ws_size,
                              hipStream_t stream) {
    const int*   tok   = (const int*)d_in[0];
    const float* emb   = (const float*)d_in[2];
    const float* pe    = (const float*)d_in[3];
    const float* ln1g  = (const float*)d_in[4];
    const float* ln1b  = (const float*)d_in[5];
    const float* Wqkv  = (const float*)d_in[6];
    const float* bqkv  = (const float*)d_in[7];
    const float* Wproj = (const float*)d_in[8];
    const float* bproj = (const float*)d_in[9];
    const float* ln2g  = (const float*)d_in[10];
    const float* ln2b  = (const float*)d_in[11];
    const float* W1    = (const float*)d_in[12];
    const float* b1    = (const float*)d_in[13];
    const float* W2    = (const float*)d_in[14];
    const float* b2    = (const float*)d_in[15];
    const float* lnfg  = (const float*)d_in[16];
    const float* lnfb  = (const float*)d_in[17];
    const float* outb  = (const float*)d_in[18];

    float* logits  = (float*)d_out;                    // [B*T, V] f32
    float* attnF   = logits + (size_t)B * T * V;       // [B*H, T, T] f32

    char* w = (char*)d_ws;
    float* x    = (float*)w;  w += (size_t)B * T * D * 4;       // 8.39 MB
    u16* lnout  = (u16*)w;    w += (size_t)B * T * D * 2;       // 4.19 MB
    u16* qkv    = (u16*)w;    w += (size_t)B * T * 3 * D * 2;   // 12.58 MB
    u16* vT     = (u16*)w;    w += (size_t)B * H * HD * T * 2;  // 4.19 MB
    u16* aout   = (u16*)w;    w += (size_t)B * T * D * 2;       // 4.19 MB
    u16* hmid   = (u16*)w;    w += (size_t)B * T * F * 2;       // 16.78 MB
    u16* WT     = (u16*)w;    w += (size_t)D * F * 2;           // 8.39 MB (per-weight shared)
    u16* pb     = (u16*)w;    w += (size_t)B * H * T * T * 2;   // 67.11 MB (probs bf16; reused as embB)
    u16* embB   = pb;                                           // live only after layer loop

    dim3 blk(256);
    k_embed<<<dim3(B * T), blk, 0, stream>>>(tok, emb, pe, x);

    for (int l = 0; l < L; l++) {
        k_lnorm<<<dim3(B * T), blk, 0, stream>>>(x, ln1g + l * D, ln1b + l * D, lnout);
        k_castT<<<dim3(3 * D / 32, D / 32), blk, 0, stream>>>(Wqkv + (size_t)l * D * 3 * D, WT, D, 3 * D);
        k_gemm_bt<0><<<dim3(B * T / 128, 3 * D / 128), blk, 0, stream>>>(
            lnout, D, WT, D, bqkv + l * 3 * D, qkv, 3 * D, D);
        if (l == L - 1)
            k_attn<true><<<dim3(T / 64, B * H), blk, 0, stream>>>(qkv, attnF, pb);
        else
            k_attn<false><<<dim3(T / 64, B * H), blk, 0, stream>>>(qkv, attnF, pb);
        k_vtrans<<<dim3(T / 32, HD / 32, B * H), blk, 0, stream>>>(qkv, vT);
        k_pv<<<dim3(T / 64, B * H), blk, 0, stream>>>(pb, vT, aout);
        k_castT<<<dim3(D / 32, D / 32), blk, 0, stream>>>(Wproj + (size_t)l * D * D, WT, D, D);
        k_gemm_bt<2><<<dim3(B * T / 128, D / 128), blk, 0, stream>>>(
            aout, D, WT, D, bproj + l * D, x, D, D);
        k_lnorm<<<dim3(B * T), blk, 0, stream>>>(x, ln2g + l * D, ln2b + l * D, lnout);
        k_castT<<<dim3(F / 32, D / 32), blk, 0, stream>>>(W1 + (size_t)l * D * F, WT, D, F);
        k_gemm_bt<1><<<dim3(B * T / 128, F / 128), blk, 0, stream>>>(
            lnout, D, WT, D, b1 + l * F, hmid, F, D);
        k_castT<<<dim3(D / 32, F / 32), blk, 0, stream>>>(W2 + (size_t)l * F * D, WT, F, D);
        k_gemm_bt<2><<<dim3(B * T / 128, D / 128), blk, 0, stream>>>(
            hmid, F, WT, F, b2 + l * D, x, D, F);
    }
    k_cast<<<dim3(V * D / 1024), blk, 0, stream>>>(emb, embB);
    k_lnorm<<<dim3(B * T), blk, 0, stream>>>(x, lnfg, lnfb, lnout);
    k_gemm_bt<3><<<dim3(B * T / 128, V / 128), blk, 0, stream>>>(
        lnout, D, embB, D, outb, logits, V, D);
}

// Round 4
// 1401.862 us; speedup vs baseline: 1.1196x; 1.1196x over previous
//
#include <hip/hip_runtime.h>
#include <cstdint>

#define DEV static __device__ __forceinline__

typedef unsigned short u16;
typedef __bf16 bf16x8 __attribute__((ext_vector_type(8)));
typedef float f32x4 __attribute__((ext_vector_type(4)));
typedef unsigned short u16x4 __attribute__((ext_vector_type(4)));

constexpr int V = 32000, D = 1024, H = 16, L = 4, F = 4096, T = 1024, B = 2;
constexpr int HD = 64;

DEV u16 f2bf(float f) {
    union { float f; uint32_t i; } c; c.f = f;
    uint32_t x = c.i;
    return (u16)((x + 0x7fffu + ((x >> 16) & 1u)) >> 16);
}
DEV bf16x8 ld8(const u16* p) { return *reinterpret_cast<const bf16x8*>(p); }

DEV void gl16(const void* g, void* l) {
    __builtin_amdgcn_global_load_lds((const __attribute__((address_space(1))) void*)g,
                                     (__attribute__((address_space(3))) void*)l, 16, 0, 0);
}

// ---------------- embedding: x = emb[tok] + pe (all f32) ----------------
__global__ __launch_bounds__(256) void k_embed(const int* __restrict__ tok,
        const float* __restrict__ emb, const float* __restrict__ pe, float* __restrict__ x) {
    int i = blockIdx.x;              // b*T + t
    int t = i & (T - 1);
    int v = tok[i];
    const f32x4* er = (const f32x4*)(emb + (size_t)v * D);
    const f32x4* pr = (const f32x4*)(pe + (size_t)t * D);
    f32x4* xr = (f32x4*)(x + (size_t)i * D);
    int tid = threadIdx.x;
    xr[tid] = er[tid] + pr[tid];
}

// ---------------- elementwise cast f32 -> bf16 ----------------
__global__ __launch_bounds__(256) void k_cast(const float* __restrict__ src,
        u16* __restrict__ dst) {
    int i = (blockIdx.x * 256 + threadIdx.x) * 4;
    f32x4 v = *(const f32x4*)(src + i);
    u16x4 o;
#pragma unroll
    for (int j = 0; j < 4; j++) o[j] = f2bf(v[j]);
    *(u16x4*)(dst + i) = o;
}

// ---------------- layernorm: f32 in -> bf16 out ----------------
__global__ __launch_bounds__(256) void k_lnorm(const float* __restrict__ x,
        const float* __restrict__ g, const float* __restrict__ b, u16* __restrict__ out) {
    int row = blockIdx.x;
    int tid = threadIdx.x;
    f32x4 v = ((const f32x4*)(x + (size_t)row * D))[tid];
    float s = v[0] + v[1] + v[2] + v[3];
    float s2 = v[0]*v[0] + v[1]*v[1] + v[2]*v[2] + v[3]*v[3];
#pragma unroll
    for (int m = 1; m < 64; m <<= 1) { s += __shfl_xor(s, m); s2 += __shfl_xor(s2, m); }
    __shared__ float ps[4], ps2[4];
    int wave = tid >> 6;
    if ((tid & 63) == 0) { ps[wave] = s; ps2[wave] = s2; }
    __syncthreads();
    s = ps[0] + ps[1] + ps[2] + ps[3];
    s2 = ps2[0] + ps2[1] + ps2[2] + ps2[3];
    float mean = s * (1.f / D);
    float var = s2 * (1.f / D) - mean * mean;
    float r = rsqrtf(var + 1e-5f);
    f32x4 gg = ((const f32x4*)g)[tid];
    f32x4 bb = ((const f32x4*)b)[tid];
    u16x4 o;
#pragma unroll
    for (int j = 0; j < 4; j++) o[j] = f2bf((v[j] - mean) * r * gg[j] + bb[j]);
    ((u16x4*)(out + (size_t)row * D))[tid] = o;
}

// ---------------- batched transpose+cast of one layer's 4 weights ----------------
// wt layout: [WqkvT 3D*D][WprojT D*D][W1T F*D][W2T D*F]
__global__ __launch_bounds__(256) void k_castT4(const float* __restrict__ Wqkv,
        const float* __restrict__ Wproj, const float* __restrict__ W1,
        const float* __restrict__ W2, u16* __restrict__ wt) {
    int bid = blockIdx.x;
    const float* src; u16* dst; int Rr, Cc, t;
    if (bid < 3072)      { src = Wqkv;  dst = wt;                   Rr = D; Cc = 3 * D; t = bid; }
    else if (bid < 4096) { src = Wproj; dst = wt + 3 * D * D;       Rr = D; Cc = D;     t = bid - 3072; }
    else if (bid < 8192) { src = W1;    dst = wt + 4 * D * D;       Rr = D; Cc = F;     t = bid - 4096; }
    else                 { src = W2;    dst = wt + 4 * D * D + D * F; Rr = F; Cc = D;   t = bid - 8192; }
    int ntx = Cc >> 5;
    int c0 = (t % ntx) * 32, r0 = (t / ntx) * 32;
    __shared__ u16 tl[32][33];
    int x = threadIdx.x & 31, y = threadIdx.x >> 5;
#pragma unroll
    for (int i = 0; i < 4; i++)
        tl[y + i * 8][x] = f2bf(src[(size_t)(r0 + y + i * 8) * Cc + c0 + x]);
    __syncthreads();
#pragma unroll
    for (int i = 0; i < 4; i++)
        dst[(size_t)(c0 + y + i * 8) * Rr + r0 + x] = tl[x][y + i * 8];
}

// ---------------- V^T extraction: vT[b,h,hd,t] = qkv_v[b,t,h,hd] (bf16) ----------------
__global__ __launch_bounds__(256) void k_vtrans(const u16* __restrict__ qkv, u16* __restrict__ vT) {
    int bh = blockIdx.z; int b = bh >> 4, h = bh & 15;
    int t0 = blockIdx.x * 32, d0 = blockIdx.y * 32;
    __shared__ u16 tl[32][33];
    int x = threadIdx.x & 31, y = threadIdx.x >> 5;
#pragma unroll
    for (int i = 0; i < 4; i++)
        tl[y + i * 8][x] = qkv[(size_t)(b * T + t0 + y + i * 8) * (3 * D) + 2 * D + h * HD + d0 + x];
    __syncthreads();
#pragma unroll
    for (int i = 0; i < 4; i++)
        vT[((size_t)bh * HD + d0 + y + i * 8) * T + t0 + x] = tl[x][y + i * 8];
}

// ---------------- GEMM: C[M,N] = A[M,K](bf16) @ Bt[N,K](bf16)^T + bias(f32) ----------------
// EPI: 0 = store bf16, 1 = GELU->bf16, 2 = add into f32 residual, 3 = store f32
template <int EPI>
__global__ __launch_bounds__(256) void k_gemm_bt(
        const u16* __restrict__ A, int lda,
        const u16* __restrict__ Bt, int ldb,
        const float* __restrict__ bias,
        void* __restrict__ Cv, int ldc, int K) {
    __shared__ u16 tA[128 * 32];
    __shared__ u16 tB[128 * 32];
    // XCD-chunked bijective swizzle (m204): contiguous wg chunk per XCD -> B-panel L2 reuse
    int gm = gridDim.x;
    int nwg = gm * gridDim.y;
    int orig = blockIdx.y * gm + blockIdx.x;
    int xcd = orig & 7, idx = orig >> 3;
    int q = nwg >> 3, rr = nwg & 7;
    int wg = (xcd < rr ? xcd * (q + 1) : rr * (q + 1) + (xcd - rr) * q) + idx;
    int m0 = (wg % gm) * 128, n0 = (wg / gm) * 128;
    int tid = threadIdx.x, wave = tid >> 6, lane = tid & 63;
    int llo = lane & 15, lhi = lane >> 4;
    int wr = wave >> 1, wc = wave & 1;
    f32x4 acc[4][4] = {};
    for (int k0 = 0; k0 < K; k0 += 32) {
        for (int c = wave; c < 8; c += 4) {
            int e = (c * 64 + lane) * 8;
            int row = e >> 5, col = e & 31;
            gl16(A  + (size_t)(m0 + row) * lda + k0 + col, &tA[c * 512]);
            gl16(Bt + (size_t)(n0 + row) * ldb + k0 + col, &tB[c * 512]);
        }
        __syncthreads();
        bf16x8 af[4], bfr[4];
#pragma unroll
        for (int mi = 0; mi < 4; mi++) af[mi] = ld8(&tA[(wr * 64 + mi * 16 + llo) * 32 + lhi * 8]);
#pragma unroll
        for (int ni = 0; ni < 4; ni++) bfr[ni] = ld8(&tB[(wc * 64 + ni * 16 + llo) * 32 + lhi * 8]);
#pragma unroll
        for (int mi = 0; mi < 4; mi++)
#pragma unroll
            for (int ni = 0; ni < 4; ni++)
                acc[mi][ni] = __builtin_amdgcn_mfma_f32_16x16x32_bf16(af[mi], bfr[ni], acc[mi][ni], 0, 0, 0);
        __syncthreads();
    }
#pragma unroll
    for (int ni = 0; ni < 4; ni++) {
        int col = n0 + wc * 64 + ni * 16 + llo;
        float bb = bias[col];
#pragma unroll
        for (int mi = 0; mi < 4; mi++) {
#pragma unroll
            for (int r = 0; r < 4; r++) {
                int row = m0 + wr * 64 + mi * 16 + lhi * 4 + r;
                float o = acc[mi][ni][r] + bb;
                if (EPI == 1) o = 0.5f * o * (1.f + erff(o * 0.70710678118f));
                if (EPI == 2) {
                    ((float*)Cv)[(size_t)row * ldc + col] += o;
                } else if (EPI == 3) {
                    ((float*)Cv)[(size_t)row * ldc + col] = o;
                } else {
                    ((u16*)Cv)[(size_t)row * ldc + col] = f2bf(o);
                }
            }
        }
    }
}

// ---------------- fused flash attention: qkv -> aout (bf16), no prob materialization ----
// Swapped QK^T: mfma(K,Q) so each lane owns q-row = i0 + (lane&15); P staged per-wave in LDS.
__global__ __launch_bounds__(256) void k_fattn(const u16* __restrict__ qkv,
        const u16* __restrict__ vT, u16* __restrict__ out) {
    __shared__ u16 plds[4][16 * 40];     // per-wave 16 q-rows x 32 k, stride 40 u16 (80B)
    int bh = blockIdx.y; int b = bh >> 4, h = bh & 15;
    int tid = threadIdx.x, wave = tid >> 6, lane = tid & 63;
    int llo = lane & 15, lhi = lane >> 4;
    int i0 = blockIdx.x * 64 + wave * 16;
    const u16* qb = qkv + (size_t)b * T * (3 * D) + h * HD;
    const u16* kb = qb + D;
    const u16* vt = vT + (size_t)bh * HD * T;
    bf16x8 q0 = ld8(qb + (size_t)(i0 + llo) * (3 * D) + lhi * 8);
    bf16x8 q1 = ld8(qb + (size_t)(i0 + llo) * (3 * D) + 32 + lhi * 8);
    int qrow = i0 + llo;
    float m = -3e38f, s = 0.f;           // row stats for q-row = qrow (dup across lhi)
    f32x4 oacc[4] = {};                  // O[q = lhi*4+r][d = n*16+llo]
    u16* pw = &plds[wave][0];
    for (int k0 = 0; k0 < i0 + 16; k0 += 32) {
        f32x4 sc0 = {}, sc1 = {};
        {
            bf16x8 kf0 = ld8(kb + (size_t)(k0 + llo) * (3 * D) + lhi * 8);
            bf16x8 kf1 = ld8(kb + (size_t)(k0 + llo) * (3 * D) + 32 + lhi * 8);
            sc0 = __builtin_amdgcn_mfma_f32_16x16x32_bf16(kf0, q0, sc0, 0, 0, 0);
            sc0 = __builtin_amdgcn_mfma_f32_16x16x32_bf16(kf1, q1, sc0, 0, 0, 0);
        }
        if (k0 + 16 < i0 + 16) {
            bf16x8 kf0 = ld8(kb + (size_t)(k0 + 16 + llo) * (3 * D) + lhi * 8);
            bf16x8 kf1 = ld8(kb + (size_t)(k0 + 16 + llo) * (3 * D) + 32 + lhi * 8);
            sc1 = __builtin_amdgcn_mfma_f32_16x16x32_bf16(kf0, q0, sc1, 0, 0, 0);
            sc1 = __builtin_amdgcn_mfma_f32_16x16x32_bf16(kf1, q1, sc1, 0, 0, 0);
        }
        // lane value (hf,r): S[q=qrow][k = k0 + hf*16 + lhi*4 + r]
        float vv[8]; float mx = m;
#pragma unroll
        for (int hf = 0; hf < 2; hf++)
#pragma unroll
            for (int r = 0; r < 4; r++) {
                int k = k0 + hf * 16 + lhi * 4 + r;
                float x = (hf ? sc1[r] : sc0[r]) * 0.125f;
                float v = (k <= qrow) ? x : -3e38f;
                vv[hf * 4 + r] = v;
                mx = fmaxf(mx, v);
            }
        mx = fmaxf(mx, __shfl_xor(mx, 16));
        mx = fmaxf(mx, __shfl_xor(mx, 32));
        float p[8]; float ps = 0.f;
#pragma unroll
        for (int j = 0; j < 8; j++) { p[j] = __expf(vv[j] - mx); ps += p[j]; }
        ps += __shfl_xor(ps, 16);
        ps += __shfl_xor(ps, 32);
        float scale = __expf(m - mx);
        s = s * scale + ps;
        m = mx;
        // rescale O: factor for q_local = lhi*4+r lives at lane (lhi*4+r)
        float sr[4];
#pragma unroll
        for (int r = 0; r < 4; r++) sr[r] = __shfl(scale, lhi * 4 + r);
#pragma unroll
        for (int n = 0; n < 4; n++)
#pragma unroll
            for (int r = 0; r < 4; r++) oacc[n][r] *= sr[r];
        // pack P (bf16) into per-wave LDS: row llo, col hf*16 + lhi*4 + r
#pragma unroll
        for (int hf = 0; hf < 2; hf++) {
            u16x4 pk;
#pragma unroll
            for (int r = 0; r < 4; r++) pk[r] = f2bf(p[hf * 4 + r]);
            *(u16x4*)(pw + llo * 40 + hf * 16 + lhi * 4) = pk;
        }
        // PV: A-frag = P[q=llo][k=lhi*8..+7] from LDS; B-frag = V^T[d=n*16+llo][k]
        bf16x8 pa = ld8(pw + llo * 40 + lhi * 8);
#pragma unroll
        for (int n = 0; n < 4; n++) {
            bf16x8 vb = ld8(vt + (size_t)(n * 16 + llo) * T + k0 + lhi * 8);
            oacc[n] = __builtin_amdgcn_mfma_f32_16x16x32_bf16(pa, vb, oacc[n], 0, 0, 0);
        }
    }
    float inv = 1.f / s;
    float ir[4];
#pragma unroll
    for (int r = 0; r < 4; r++) ir[r] = __shfl(inv, lhi * 4 + r);
#pragma unroll
    for (int n = 0; n < 4; n++)
#pragma unroll
        for (int r = 0; r < 4; r++) {
            int i = i0 + lhi * 4 + r, c = n * 16 + llo;
            out[(size_t)(b * T + i) * D + h * HD + c] = f2bf(oacc[n][r] * inv * 0.f + oacc[n][r] * ir[r]);
        }
}

// ---------------- last-layer probs: QK^T + softmax -> attnF (f32) ----------------
__global__ __launch_bounds__(256) void k_attnp(const u16* __restrict__ qkv,
        float* __restrict__ attn_f32) {
    int bh = blockIdx.y; int b = bh >> 4, h = bh & 15;
    int tid = threadIdx.x, wave = tid >> 6, lane = tid & 63;
    int llo = lane & 15, lhi = lane >> 4;
    int i0 = blockIdx.x * 64 + wave * 16;
    const u16* qb = qkv + (size_t)b * T * (3 * D) + h * HD;
    const u16* kb = qb + D;
    bf16x8 a0 = ld8(qb + (size_t)(i0 + llo) * (3 * D) + lhi * 8);
    bf16x8 a1 = ld8(qb + (size_t)(i0 + llo) * (3 * D) + 32 + lhi * 8);
    float mloc[4], sloc[4];
#pragma unroll
    for (int r = 0; r < 4; r++) { mloc[r] = -1e30f; sloc[r] = 0.f; }
    for (int j0 = 0; j0 <= i0 + 15; j0 += 16) {
        bf16x8 b0 = ld8(kb + (size_t)(j0 + llo) * (3 * D) + lhi * 8);
        bf16x8 b1 = ld8(kb + (size_t)(j0 + llo) * (3 * D) + 32 + lhi * 8);
        f32x4 acc = {};
        acc = __builtin_amdgcn_mfma_f32_16x16x32_bf16(a0, b0, acc, 0, 0, 0);
        acc = __builtin_amdgcn_mfma_f32_16x16x32_bf16(a1, b1, acc, 0, 0, 0);
#pragma unroll
        for (int r = 0; r < 4; r++) {
            int i = i0 + lhi * 4 + r;
            int j = j0 + llo;
            float vv = (j <= i) ? acc[r] * 0.125f : -1e9f;
            float nm = fmaxf(mloc[r], vv);
            sloc[r] = sloc[r] * __expf(mloc[r] - nm) + __expf(vv - nm);
            mloc[r] = nm;
        }
    }
    float Mf[4], Sinv[4];
#pragma unroll
    for (int r = 0; r < 4; r++) {
        float M = mloc[r], S = sloc[r];
#pragma unroll
        for (int m = 1; m < 16; m <<= 1) {
            float Mo = __shfl_xor(M, m), So = __shfl_xor(S, m);
            float nm = fmaxf(M, Mo);
            S = S * __expf(M - nm) + So * __expf(Mo - nm);
            M = nm;
        }
        Mf[r] = M; Sinv[r] = 1.f / S;
    }
    float* ar = attn_f32 + (size_t)bh * T * T;
    for (int j0 = 0; j0 < T; j0 += 16) {
        int j = j0 + llo;
        if (j0 <= i0 + 15) {
            bf16x8 b0 = ld8(kb + (size_t)(j0 + llo) * (3 * D) + lhi * 8);
            bf16x8 b1 = ld8(kb + (size_t)(j0 + llo) * (3 * D) + 32 + lhi * 8);
            f32x4 acc = {};
            acc = __builtin_amdgcn_mfma_f32_16x16x32_bf16(a0, b0, acc, 0, 0, 0);
            acc = __builtin_amdgcn_mfma_f32_16x16x32_bf16(a1, b1, acc, 0, 0, 0);
#pragma unroll
            for (int r = 0; r < 4; r++) {
                int i = i0 + lhi * 4 + r;
                float p = (j <= i) ? __expf(acc[r] * 0.125f - Mf[r]) * Sinv[r] : 0.f;
                ar[(size_t)i * T + j] = p;
            }
        } else {
#pragma unroll
            for (int r = 0; r < 4; r++) {
                int i = i0 + lhi * 4 + r;
                ar[(size_t)i * T + j] = 0.f;
            }
        }
    }
}

extern "C" void kernel_launch(void* const* d_in, const int* in_sizes, int n_in,
                              void* d_out, int out_size, void* d_ws, size_t ws_size,
                              hipStream_t stream) {
    const int*   tok   = (const int*)d_in[0];
    const float* emb   = (const float*)d_in[2];
    const float* pe    = (const float*)d_in[3];
    const float* ln1g  = (const float*)d_in[4];
    const float* ln1b  = (const float*)d_in[5];
    const float* Wqkv  = (const float*)d_in[6];
    const float* bqkv  = (const float*)d_in[7];
    const float* Wproj = (const float*)d_in[8];
    const float* bproj = (const float*)d_in[9];
    const float* ln2g  = (const float*)d_in[10];
    const float* ln2b  = (const float*)d_in[11];
    const float* W1    = (const float*)d_in[12];
    const float* b1    = (const float*)d_in[13];
    const float* W2    = (const float*)d_in[14];
    const float* b2    = (const float*)d_in[15];
    const float* lnfg  = (const float*)d_in[16];
    const float* lnfb  = (const float*)d_in[17];
    const float* outb  = (const float*)d_in[18];

    float* logits  = (float*)d_out;                    // [B*T, V] f32
    float* attnF   = logits + (size_t)B * T * V;       // [B*H, T, T] f32

    char* w = (char*)d_ws;
    float* x    = (float*)w;  w += (size_t)B * T * D * 4;       // 8.39 MB
    u16* lnout  = (u16*)w;    w += (size_t)B * T * D * 2;       // 4.19 MB
    u16* qkv    = (u16*)w;    w += (size_t)B * T * 3 * D * 2;   // 12.58 MB
    u16* vT     = (u16*)w;    w += (size_t)B * H * HD * T * 2;  // 4.19 MB
    u16* aout   = (u16*)w;    w += (size_t)B * T * D * 2;       // 4.19 MB
    char* tail = w;
    u16* hmid   = (u16*)w;    w += (size_t)B * T * F * 2;       // 16.78 MB
    u16* WTL    = (u16*)w;                                      // 25.17 MB (per-layer weights^T)
    u16* embB   = (u16*)tail;                                   // 65.54 MB, aliases hmid+WTL (post-loop)

    dim3 blk(256);
    k_embed<<<dim3(B * T), blk, 0, stream>>>(tok, emb, pe, x);

    for (int l = 0; l < L; l++) {
        k_castT4<<<dim3(12288), blk, 0, stream>>>(
            Wqkv + (size_t)l * D * 3 * D, Wproj + (size_t)l * D * D,
            W1 + (size_t)l * D * F, W2 + (size_t)l * F * D, WTL);
        k_lnorm<<<dim3(B * T), blk, 0, stream>>>(x, ln1g + l * D, ln1b + l * D, lnout);
        k_gemm_bt<0><<<dim3(B * T / 128, 3 * D / 128), blk, 0, stream>>>(
            lnout, D, WTL, D, bqkv + l * 3 * D, qkv, 3 * D, D);
        k_vtrans<<<dim3(T / 32, HD / 32, B * H), blk, 0, stream>>>(qkv, vT);
        k_fattn<<<dim3(T / 64, B * H), blk, 0, stream>>>(qkv, vT, aout);
        if (l == L - 1)
            k_attnp<<<dim3(T / 64, B * H), blk, 0, stream>>>(qkv, attnF);
        k_gemm_bt<2><<<dim3(B * T / 128, D / 128), blk, 0, stream>>>(
            aout, D, WTL + (size_t)3 * D * D, D, bproj + l * D, x, D, D);
        k_lnorm<<<dim3(B * T), blk, 0, stream>>>(x, ln2g + l * D, ln2b + l * D, lnout);
        k_gemm_bt<1><<<dim3(B * T / 128, F / 128), blk, 0, stream>>>(
            lnout, D, WTL + (size_t)4 * D * D, D, b1 + l * F, hmid, F, D);
        k_gemm_bt<2><<<dim3(B * T / 128, D / 128), blk, 0, stream>>>(
            hmid, F, WTL + (size_t)4 * D * D + D * F, F, b2 + l * D, x, D, F);
    }
    k_cast<<<dim3(V * D / 1024), blk, 0, stream>>>(emb, embB);
    k_lnorm<<<dim3(B * T), blk, 0, stream>>>(x, lnfg, lnfb, lnout);
    k_gemm_bt<3><<<dim3(B * T / 128, V / 128), blk, 0, stream>>>(
        lnout, D, embB, D, outb, logits, V, D);
}

// Round 5
// 1106.246 us; speedup vs baseline: 1.4188x; 1.2672x over previous
//
#include <hip/hip_runtime.h>
#include <cstdint>

#define DEV static __device__ __forceinline__

typedef unsigned short u16;
typedef __bf16 bf16x8 __attribute__((ext_vector_type(8)));
typedef float f32x4 __attribute__((ext_vector_type(4)));
typedef unsigned short u16x4 __attribute__((ext_vector_type(4)));

constexpr int V = 32000, D = 1024, H = 16, L = 4, F = 4096, T = 1024, B = 2;
constexpr int HD = 64;

DEV u16 f2bf(float f) {
    union { float f; uint32_t i; } c; c.f = f;
    uint32_t x = c.i;
    return (u16)((x + 0x7fffu + ((x >> 16) & 1u)) >> 16);
}
DEV bf16x8 ld8(const u16* p) { return *reinterpret_cast<const bf16x8*>(p); }

DEV void gl16(const void* g, void* l) {
    __builtin_amdgcn_global_load_lds((const __attribute__((address_space(1))) void*)g,
                                     (__attribute__((address_space(3))) void*)l, 16, 0, 0);
}

// ---------------- embedding + ln1(layer0): x = emb[tok]+pe; lnout = LN(x) ----------------
__global__ __launch_bounds__(256) void k_embln(const int* __restrict__ tok,
        const float* __restrict__ emb, const float* __restrict__ pe,
        const float* __restrict__ g, const float* __restrict__ b,
        float* __restrict__ x, u16* __restrict__ out) {
    int row = blockIdx.x, tid = threadIdx.x;
    int t = row & (T - 1);
    int vv = tok[row];
    f32x4 v = ((const f32x4*)(emb + (size_t)vv * D))[tid] + ((const f32x4*)(pe + (size_t)t * D))[tid];
    ((f32x4*)(x + (size_t)row * D))[tid] = v;
    float s = v[0] + v[1] + v[2] + v[3];
    float s2 = v[0]*v[0] + v[1]*v[1] + v[2]*v[2] + v[3]*v[3];
#pragma unroll
    for (int m = 1; m < 64; m <<= 1) { s += __shfl_xor(s, m); s2 += __shfl_xor(s2, m); }
    __shared__ float ps[4], ps2[4];
    int wave = tid >> 6;
    if ((tid & 63) == 0) { ps[wave] = s; ps2[wave] = s2; }
    __syncthreads();
    s = ps[0] + ps[1] + ps[2] + ps[3];
    s2 = ps2[0] + ps2[1] + ps2[2] + ps2[3];
    float mean = s * (1.f / D);
    float var = s2 * (1.f / D) - mean * mean;
    float r = rsqrtf(var + 1e-5f);
    f32x4 gg = ((const f32x4*)g)[tid];
    f32x4 bb = ((const f32x4*)b)[tid];
    u16x4 o;
#pragma unroll
    for (int j = 0; j < 4; j++) o[j] = f2bf((v[j] - mean) * r * gg[j] + bb[j]);
    ((u16x4*)(out + (size_t)row * D))[tid] = o;
}

// ---------------- splitK reduce + bias + residual + LayerNorm ----------------
template <int S>
__global__ __launch_bounds__(256) void k_redln(const float* __restrict__ pp,
        const float* __restrict__ bias, float* __restrict__ x,
        const float* __restrict__ g, const float* __restrict__ b,
        u16* __restrict__ out) {
    int row = blockIdx.x, tid = threadIdx.x;
    f32x4 v = ((const f32x4*)(x + (size_t)row * D))[tid];
#pragma unroll
    for (int s = 0; s < S; s++)
        v += ((const f32x4*)(pp + ((size_t)s * (B * T) + row) * D))[tid];
    v += ((const f32x4*)bias)[tid];
    ((f32x4*)(x + (size_t)row * D))[tid] = v;
    float s = v[0] + v[1] + v[2] + v[3];
    float s2 = v[0]*v[0] + v[1]*v[1] + v[2]*v[2] + v[3]*v[3];
#pragma unroll
    for (int m = 1; m < 64; m <<= 1) { s += __shfl_xor(s, m); s2 += __shfl_xor(s2, m); }
    __shared__ float ps[4], ps2[4];
    int wave = tid >> 6;
    if ((tid & 63) == 0) { ps[wave] = s; ps2[wave] = s2; }
    __syncthreads();
    s = ps[0] + ps[1] + ps[2] + ps[3];
    s2 = ps2[0] + ps2[1] + ps2[2] + ps2[3];
    float mean = s * (1.f / D);
    float var = s2 * (1.f / D) - mean * mean;
    float r = rsqrtf(var + 1e-5f);
    f32x4 gg = ((const f32x4*)g)[tid];
    f32x4 bb = ((const f32x4*)b)[tid];
    u16x4 o;
#pragma unroll
    for (int j = 0; j < 4; j++) o[j] = f2bf((v[j] - mean) * r * gg[j] + bb[j]);
    ((u16x4*)(out + (size_t)row * D))[tid] = o;
}

// ---------------- elementwise cast f32 -> bf16 ----------------
__global__ __launch_bounds__(256) void k_cast(const float* __restrict__ src,
        u16* __restrict__ dst) {
    int i = (blockIdx.x * 256 + threadIdx.x) * 4;
    f32x4 v = *(const f32x4*)(src + i);
    u16x4 o;
#pragma unroll
    for (int j = 0; j < 4; j++) o[j] = f2bf(v[j]);
    *(u16x4*)(dst + i) = o;
}

// ---------------- batched transpose+cast of one layer's 4 weights ----------------
// wt layout: [WqkvT 3D*D][WprojT D*D][W1T F*D][W2T D*F]
__global__ __launch_bounds__(256) void k_castT4(const float* __restrict__ Wqkv,
        const float* __restrict__ Wproj, const float* __restrict__ W1,
        const float* __restrict__ W2, u16* __restrict__ wt) {
    int bid = blockIdx.x;
    const float* src; u16* dst; int Rr, Cc, t;
    if (bid < 3072)      { src = Wqkv;  dst = wt;                   Rr = D; Cc = 3 * D; t = bid; }
    else if (bid < 4096) { src = Wproj; dst = wt + 3 * D * D;       Rr = D; Cc = D;     t = bid - 3072; }
    else if (bid < 8192) { src = W1;    dst = wt + 4 * D * D;       Rr = D; Cc = F;     t = bid - 4096; }
    else                 { src = W2;    dst = wt + 4 * D * D + D * F; Rr = F; Cc = D;   t = bid - 8192; }
    int ntx = Cc >> 5;
    int c0 = (t % ntx) * 32, r0 = (t / ntx) * 32;
    __shared__ u16 tl[32][33];
    int x = threadIdx.x & 31, y = threadIdx.x >> 5;
#pragma unroll
    for (int i = 0; i < 4; i++)
        tl[y + i * 8][x] = f2bf(src[(size_t)(r0 + y + i * 8) * Cc + c0 + x]);
    __syncthreads();
#pragma unroll
    for (int i = 0; i < 4; i++)
        dst[(size_t)(c0 + y + i * 8) * Rr + r0 + x] = tl[x][y + i * 8];
}

// ---------------- GEMM: C[M,N] = A[M,K](bf16) @ Bt[N,K](bf16)^T + bias(f32) ----------------
// EPI: 0 = store bf16 (VT: V cols -> vT instead), 1 = GELU->bf16, 3 = store f32,
//      4 = f32 partial at pp + blockIdx.z*2048*ldc (no bias), K = per-split K
template <int EPI, bool VT>
__global__ __launch_bounds__(256) void k_gemm_bt(
        const u16* __restrict__ A, int lda,
        const u16* __restrict__ Bt, int ldb,
        const float* __restrict__ bias,
        void* __restrict__ Cv, int ldc, int K, u16* __restrict__ vT) {
    __shared__ u16 tA[128 * 32];
    __shared__ u16 tB[128 * 32];
    // XCD-chunked bijective swizzle (m204)
    int gm = gridDim.x;
    int nwg = gm * gridDim.y;
    int orig = blockIdx.y * gm + blockIdx.x;
    int xcd = orig & 7, idx = orig >> 3;
    int q = nwg >> 3, rr = nwg & 7;
    int wg = (xcd < rr ? xcd * (q + 1) : rr * (q + 1) + (xcd - rr) * q) + idx;
    int m0 = (wg % gm) * 128, n0 = (wg / gm) * 128;
    int koff = (EPI == 4) ? blockIdx.z * K : 0;
    int tid = threadIdx.x, wave = tid >> 6, lane = tid & 63;
    int llo = lane & 15, lhi = lane >> 4;
    int wr = wave >> 1, wc = wave & 1;
    f32x4 acc[4][4] = {};
    for (int k0 = 0; k0 < K; k0 += 32) {
        for (int c = wave; c < 8; c += 4) {
            int e = (c * 64 + lane) * 8;
            int row = e >> 5, col = e & 31;
            gl16(A  + (size_t)(m0 + row) * lda + koff + k0 + col, &tA[c * 512]);
            gl16(Bt + (size_t)(n0 + row) * ldb + koff + k0 + col, &tB[c * 512]);
        }
        __syncthreads();
        bf16x8 af[4], bfr[4];
#pragma unroll
        for (int mi = 0; mi < 4; mi++) af[mi] = ld8(&tA[(wr * 64 + mi * 16 + llo) * 32 + lhi * 8]);
#pragma unroll
        for (int ni = 0; ni < 4; ni++) bfr[ni] = ld8(&tB[(wc * 64 + ni * 16 + llo) * 32 + lhi * 8]);
#pragma unroll
        for (int mi = 0; mi < 4; mi++)
#pragma unroll
            for (int ni = 0; ni < 4; ni++)
                acc[mi][ni] = __builtin_amdgcn_mfma_f32_16x16x32_bf16(af[mi], bfr[ni], acc[mi][ni], 0, 0, 0);
        __syncthreads();
    }
#pragma unroll
    for (int ni = 0; ni < 4; ni++) {
        int col = n0 + wc * 64 + ni * 16 + llo;
        float bb = 0.f;
        if (EPI != 4) bb = bias[col];
#pragma unroll
        for (int mi = 0; mi < 4; mi++) {
            int row0 = m0 + wr * 64 + mi * 16 + lhi * 4;
            if (VT && col >= 2 * D) {
                // write V^T: vT[b*16 + (col-2D)/64][(col-2D)&63][t], 4 consecutive t
                int dv = col - 2 * D;
                int b_ = row0 >> 10, t_ = row0 & (T - 1);
                u16x4 pk;
#pragma unroll
                for (int r = 0; r < 4; r++) pk[r] = f2bf(acc[mi][ni][r] + bb);
                *(u16x4*)(vT + ((size_t)(b_ * 16 + (dv >> 6)) * HD + (dv & 63)) * T + t_) = pk;
            } else {
#pragma unroll
                for (int r = 0; r < 4; r++) {
                    int row = row0 + r;
                    float o = acc[mi][ni][r] + bb;
                    if (EPI == 1) o = 0.5f * o * (1.f + erff(o * 0.70710678118f));
                    if (EPI == 3) {
                        ((float*)Cv)[(size_t)row * ldc + col] = o;
                    } else if (EPI == 4) {
                        ((float*)Cv)[((size_t)blockIdx.z * (B * T) + row) * ldc + col] = o;
                    } else {
                        ((u16*)Cv)[(size_t)row * ldc + col] = f2bf(o);
                    }
                }
            }
        }
    }
}

// ---------------- fused flash attention (+ optional f32 prob write for last layer) ----
// Swapped QK^T: mfma(K,Q) so lane owns q-row = i0 + (lane&15); P staged per-wave in LDS.
template <int PW>
__global__ __launch_bounds__(256) void k_fattn(const u16* __restrict__ qkv,
        const u16* __restrict__ vT, u16* __restrict__ out, float* __restrict__ attnF) {
    __shared__ u16 plds[4][16 * 40];     // per-wave 16 q-rows x 32 k, stride 40 u16
    int bh = blockIdx.y; int b = bh >> 4, h = bh & 15;
    int tid = threadIdx.x, wave = tid >> 6, lane = tid & 63;
    int llo = lane & 15, lhi = lane >> 4;
    int i0 = blockIdx.x * 64 + wave * 16;
    const u16* qb = qkv + (size_t)b * T * (3 * D) + h * HD;
    const u16* kb = qb + D;
    const u16* vt = vT + (size_t)bh * HD * T;
    bf16x8 q0 = ld8(qb + (size_t)(i0 + llo) * (3 * D) + lhi * 8);
    bf16x8 q1 = ld8(qb + (size_t)(i0 + llo) * (3 * D) + 32 + lhi * 8);
    int qrow = i0 + llo;
    float m = -3e38f, s = 0.f;           // row stats for q-row = qrow (dup across lhi)
    f32x4 oacc[4] = {};                  // O[q = lhi*4+r][d = n*16+llo]
    u16* pw = &plds[wave][0];
    for (int k0 = 0; k0 < i0 + 16; k0 += 32) {
        f32x4 sc0 = {}, sc1 = {};
        {
            bf16x8 kf0 = ld8(kb + (size_t)(k0 + llo) * (3 * D) + lhi * 8);
            bf16x8 kf1 = ld8(kb + (size_t)(k0 + llo) * (3 * D) + 32 + lhi * 8);
            sc0 = __builtin_amdgcn_mfma_f32_16x16x32_bf16(kf0, q0, sc0, 0, 0, 0);
            sc0 = __builtin_amdgcn_mfma_f32_16x16x32_bf16(kf1, q1, sc0, 0, 0, 0);
        }
        if (k0 + 16 < i0 + 16) {
            bf16x8 kf0 = ld8(kb + (size_t)(k0 + 16 + llo) * (3 * D) + lhi * 8);
            bf16x8 kf1 = ld8(kb + (size_t)(k0 + 16 + llo) * (3 * D) + 32 + lhi * 8);
            sc1 = __builtin_amdgcn_mfma_f32_16x16x32_bf16(kf0, q0, sc1, 0, 0, 0);
            sc1 = __builtin_amdgcn_mfma_f32_16x16x32_bf16(kf1, q1, sc1, 0, 0, 0);
        }
        float vv[8]; float mx = m;
#pragma unroll
        for (int hf = 0; hf < 2; hf++)
#pragma unroll
            for (int r = 0; r < 4; r++) {
                int k = k0 + hf * 16 + lhi * 4 + r;
                float x = (hf ? sc1[r] : sc0[r]) * 0.125f;
                float v = (k <= qrow) ? x : -3e38f;
                vv[hf * 4 + r] = v;
                mx = fmaxf(mx, v);
            }
        mx = fmaxf(mx, __shfl_xor(mx, 16));
        mx = fmaxf(mx, __shfl_xor(mx, 32));
        float p[8]; float ps = 0.f;
#pragma unroll
        for (int j = 0; j < 8; j++) { p[j] = __expf(vv[j] - mx); ps += p[j]; }
        ps += __shfl_xor(ps, 16);
        ps += __shfl_xor(ps, 32);
        float scale = __expf(m - mx);
        s = s * scale + ps;
        m = mx;
        float sr[4];
#pragma unroll
        for (int r = 0; r < 4; r++) sr[r] = __shfl(scale, lhi * 4 + r);
#pragma unroll
        for (int n = 0; n < 4; n++)
#pragma unroll
            for (int r = 0; r < 4; r++) oacc[n][r] *= sr[r];
#pragma unroll
        for (int hf = 0; hf < 2; hf++) {
            u16x4 pk;
#pragma unroll
            for (int r = 0; r < 4; r++) pk[r] = f2bf(p[hf * 4 + r]);
            *(u16x4*)(pw + llo * 40 + hf * 16 + lhi * 4) = pk;
        }
        bf16x8 pa = ld8(pw + llo * 40 + lhi * 8);
#pragma unroll
        for (int n = 0; n < 4; n++) {
            bf16x8 vb = ld8(vt + (size_t)(n * 16 + llo) * T + k0 + lhi * 8);
            oacc[n] = __builtin_amdgcn_mfma_f32_16x16x32_bf16(pa, vb, oacc[n], 0, 0, 0);
        }
    }
    float inv = 1.f / s;
    float ir[4];
#pragma unroll
    for (int r = 0; r < 4; r++) ir[r] = __shfl(inv, lhi * 4 + r);
#pragma unroll
    for (int n = 0; n < 4; n++)
#pragma unroll
        for (int r = 0; r < 4; r++) {
            int i = i0 + lhi * 4 + r, c = n * 16 + llo;
            out[(size_t)(b * T + i) * D + h * HD + c] = f2bf(oacc[n][r] * ir[r]);
        }
    if (PW) {
        // second sweep: write f32 probs for q-row = qrow over all j (zeros above diagonal)
        float* ar = attnF + ((size_t)bh * T + qrow) * T;
        for (int j0 = 0; j0 < T; j0 += 16) {
            f32x4 pv = {};
            if (j0 <= qrow) {           // some lane in this wave may need it; compute per-lane
                if (j0 < i0 + 16) {
                    bf16x8 kf0 = ld8(kb + (size_t)(j0 + llo) * (3 * D) + lhi * 8);
                    bf16x8 kf1 = ld8(kb + (size_t)(j0 + llo) * (3 * D) + 32 + lhi * 8);
                    f32x4 sc = {};
                    sc = __builtin_amdgcn_mfma_f32_16x16x32_bf16(kf0, q0, sc, 0, 0, 0);
                    sc = __builtin_amdgcn_mfma_f32_16x16x32_bf16(kf1, q1, sc, 0, 0, 0);
#pragma unroll
                    for (int r = 0; r < 4; r++) {
                        int j = j0 + lhi * 4 + r;
                        pv[r] = (j <= qrow) ? __expf(sc[r] * 0.125f - m) * inv : 0.f;
                    }
                }
            }
            *(f32x4*)(ar + j0 + lhi * 4) = pv;
        }
    }
}

extern "C" void kernel_launch(void* const* d_in, const int* in_sizes, int n_in,
                              void* d_out, int out_size, void* d_ws, size_t ws_size,
                              hipStream_t stream) {
    const int*   tok   = (const int*)d_in[0];
    const float* emb   = (const float*)d_in[2];
    const float* pe    = (const float*)d_in[3];
    const float* ln1g  = (const float*)d_in[4];
    const float* ln1b  = (const float*)d_in[5];
    const float* Wqkv  = (const float*)d_in[6];
    const float* bqkv  = (const float*)d_in[7];
    const float* Wproj = (const float*)d_in[8];
    const float* bproj = (const float*)d_in[9];
    const float* ln2g  = (const float*)d_in[10];
    const float* ln2b  = (const float*)d_in[11];
    const float* W1    = (const float*)d_in[12];
    const float* b1    = (const float*)d_in[13];
    const float* W2    = (const float*)d_in[14];
    const float* b2    = (const float*)d_in[15];
    const float* lnfg  = (const float*)d_in[16];
    const float* lnfb  = (const float*)d_in[17];
    const float* outb  = (const float*)d_in[18];

    float* logits  = (float*)d_out;                    // [B*T, V] f32
    float* attnF   = logits + (size_t)B * T * V;       // [B*H, T, T] f32

    char* w = (char*)d_ws;
    float* x    = (float*)w;  w += (size_t)B * T * D * 4;       // 8.39 MB
    u16* lnout  = (u16*)w;    w += (size_t)B * T * D * 2;       // 4.19 MB
    u16* qkv    = (u16*)w;    w += (size_t)B * T * 3 * D * 2;   // 12.58 MB
    u16* vT     = (u16*)w;    w += (size_t)B * H * HD * T * 2;  // 4.19 MB
    u16* aout   = (u16*)w;    w += (size_t)B * T * D * 2;       // 4.19 MB
    char* tail = w;
    u16* hmid   = (u16*)w;    w += (size_t)B * T * F * 2;       // 16.78 MB
    u16* WTL    = (u16*)w;    w += (size_t)(5 * D * D + 2 * D * F) * 2; // 25.17 MB
    float* pp   = (float*)w;  w += (size_t)4 * B * T * D * 4;   // 33.55 MB (splitK partials)
    u16* embB   = (u16*)tail;                                   // 65.54 MB, aliases hmid+WTL+pp

    dim3 blk(256);
    k_embln<<<dim3(B * T), blk, 0, stream>>>(tok, emb, pe, ln1g, ln1b, x, lnout);

    for (int l = 0; l < L; l++) {
        k_castT4<<<dim3(12288), blk, 0, stream>>>(
            Wqkv + (size_t)l * D * 3 * D, Wproj + (size_t)l * D * D,
            W1 + (size_t)l * D * F, W2 + (size_t)l * F * D, WTL);
        k_gemm_bt<0, true><<<dim3(B * T / 128, 3 * D / 128), blk, 0, stream>>>(
            lnout, D, WTL, D, bqkv + l * 3 * D, qkv, 3 * D, D, vT);
        if (l == L - 1)
            k_fattn<1><<<dim3(T / 64, B * H), blk, 0, stream>>>(qkv, vT, aout, attnF);
        else
            k_fattn<0><<<dim3(T / 64, B * H), blk, 0, stream>>>(qkv, vT, aout, attnF);
        k_gemm_bt<4, false><<<dim3(B * T / 128, D / 128, 2), blk, 0, stream>>>(
            aout, D, WTL + (size_t)3 * D * D, D, nullptr, pp, D, D / 2, nullptr);
        k_redln<2><<<dim3(B * T), blk, 0, stream>>>(pp, bproj + l * D, x,
            ln2g + l * D, ln2b + l * D, lnout);
        k_gemm_bt<1, false><<<dim3(B * T / 128, F / 128), blk, 0, stream>>>(
            lnout, D, WTL + (size_t)4 * D * D, D, b1 + l * F, hmid, F, D, nullptr);
        k_gemm_bt<4, false><<<dim3(B * T / 128, D / 128, 4), blk, 0, stream>>>(
            hmid, F, WTL + (size_t)4 * D * D + D * F, F, nullptr, pp, D, F / 4, nullptr);
        const float* ng = (l == L - 1) ? lnfg : ln1g + (l + 1) * D;
        const float* nb = (l == L - 1) ? lnfb : ln1b + (l + 1) * D;
        k_redln<4><<<dim3(B * T), blk, 0, stream>>>(pp, b2 + l * D, x, ng, nb, lnout);
    }
    k_cast<<<dim3(V * D / 1024), blk, 0, stream>>>(emb, embB);
    k_gemm_bt<3, false><<<dim3(B * T / 128, V / 128), blk, 0, stream>>>(
        lnout, D, embB, D, outb, logits, V, D, nullptr);
}

// Round 6
// 1100.937 us; speedup vs baseline: 1.4256x; 1.0048x over previous
//
#include <hip/hip_runtime.h>
#include <cstdint>

#define DEV static __device__ __forceinline__

typedef unsigned short u16;
typedef __bf16 bf16x8 __attribute__((ext_vector_type(8)));
typedef float f32x4 __attribute__((ext_vector_type(4)));
typedef unsigned short u16x4 __attribute__((ext_vector_type(4)));

constexpr int V = 32000, D = 1024, H = 16, L = 4, F = 4096, T = 1024, B = 2;
constexpr int HD = 64;

DEV u16 f2bf(float f) {
    union { float f; uint32_t i; } c; c.f = f;
    uint32_t x = c.i;
    return (u16)((x + 0x7fffu + ((x >> 16) & 1u)) >> 16);
}
DEV bf16x8 ld8(const u16* p) { return *reinterpret_cast<const bf16x8*>(p); }

DEV void gl16(const void* g, void* l) {
    __builtin_amdgcn_global_load_lds((const __attribute__((address_space(1))) void*)g,
                                     (__attribute__((address_space(3))) void*)l, 16, 0, 0);
}

// ---------------- embedding + ln1(layer0): x = emb[tok]+pe; lnout = LN(x) ----------------
__global__ __launch_bounds__(256) void k_embln(const int* __restrict__ tok,
        const float* __restrict__ emb, const float* __restrict__ pe,
        const float* __restrict__ g, const float* __restrict__ b,
        float* __restrict__ x, u16* __restrict__ out) {
    int row = blockIdx.x, tid = threadIdx.x;
    int t = row & (T - 1);
    int vv = tok[row];
    f32x4 v = ((const f32x4*)(emb + (size_t)vv * D))[tid] + ((const f32x4*)(pe + (size_t)t * D))[tid];
    ((f32x4*)(x + (size_t)row * D))[tid] = v;
    float s = v[0] + v[1] + v[2] + v[3];
    float s2 = v[0]*v[0] + v[1]*v[1] + v[2]*v[2] + v[3]*v[3];
#pragma unroll
    for (int m = 1; m < 64; m <<= 1) { s += __shfl_xor(s, m); s2 += __shfl_xor(s2, m); }
    __shared__ float ps[4], ps2[4];
    int wave = tid >> 6;
    if ((tid & 63) == 0) { ps[wave] = s; ps2[wave] = s2; }
    __syncthreads();
    s = ps[0] + ps[1] + ps[2] + ps[3];
    s2 = ps2[0] + ps2[1] + ps2[2] + ps2[3];
    float mean = s * (1.f / D);
    float var = s2 * (1.f / D) - mean * mean;
    float r = rsqrtf(var + 1e-5f);
    f32x4 gg = ((const f32x4*)g)[tid];
    f32x4 bb = ((const f32x4*)b)[tid];
    u16x4 o;
#pragma unroll
    for (int j = 0; j < 4; j++) o[j] = f2bf((v[j] - mean) * r * gg[j] + bb[j]);
    ((u16x4*)(out + (size_t)row * D))[tid] = o;
}

// ---------------- splitK reduce + bias + residual + LayerNorm ----------------
template <int S>
__global__ __launch_bounds__(256) void k_redln(const float* __restrict__ pp,
        const float* __restrict__ bias, float* __restrict__ x,
        const float* __restrict__ g, const float* __restrict__ b,
        u16* __restrict__ out) {
    int row = blockIdx.x, tid = threadIdx.x;
    f32x4 v = ((const f32x4*)(x + (size_t)row * D))[tid];
#pragma unroll
    for (int s = 0; s < S; s++)
        v += ((const f32x4*)(pp + ((size_t)s * (B * T) + row) * D))[tid];
    v += ((const f32x4*)bias)[tid];
    ((f32x4*)(x + (size_t)row * D))[tid] = v;
    float s = v[0] + v[1] + v[2] + v[3];
    float s2 = v[0]*v[0] + v[1]*v[1] + v[2]*v[2] + v[3]*v[3];
#pragma unroll
    for (int m = 1; m < 64; m <<= 1) { s += __shfl_xor(s, m); s2 += __shfl_xor(s2, m); }
    __shared__ float ps[4], ps2[4];
    int wave = tid >> 6;
    if ((tid & 63) == 0) { ps[wave] = s; ps2[wave] = s2; }
    __syncthreads();
    s = ps[0] + ps[1] + ps[2] + ps[3];
    s2 = ps2[0] + ps2[1] + ps2[2] + ps2[3];
    float mean = s * (1.f / D);
    float var = s2 * (1.f / D) - mean * mean;
    float r = rsqrtf(var + 1e-5f);
    f32x4 gg = ((const f32x4*)g)[tid];
    f32x4 bb = ((const f32x4*)b)[tid];
    u16x4 o;
#pragma unroll
    for (int j = 0; j < 4; j++) o[j] = f2bf((v[j] - mean) * r * gg[j] + bb[j]);
    ((u16x4*)(out + (size_t)row * D))[tid] = o;
}

// ---------------- elementwise cast f32 -> bf16 ----------------
__global__ __launch_bounds__(256) void k_cast(const float* __restrict__ src,
        u16* __restrict__ dst) {
    int i = (blockIdx.x * 256 + threadIdx.x) * 4;
    f32x4 v = *(const f32x4*)(src + i);
    u16x4 o;
#pragma unroll
    for (int j = 0; j < 4; j++) o[j] = f2bf(v[j]);
    *(u16x4*)(dst + i) = o;
}

// ---------------- batched transpose+cast of one layer's 4 weights ----------------
// wt layout: [WqkvT 3D*D][WprojT D*D][W1T F*D][W2T D*F]
__global__ __launch_bounds__(256) void k_castT4(const float* __restrict__ Wqkv,
        const float* __restrict__ Wproj, const float* __restrict__ W1,
        const float* __restrict__ W2, u16* __restrict__ wt) {
    int bid = blockIdx.x;
    const float* src; u16* dst; int Rr, Cc, t;
    if (bid < 3072)      { src = Wqkv;  dst = wt;                   Rr = D; Cc = 3 * D; t = bid; }
    else if (bid < 4096) { src = Wproj; dst = wt + 3 * D * D;       Rr = D; Cc = D;     t = bid - 3072; }
    else if (bid < 8192) { src = W1;    dst = wt + 4 * D * D;       Rr = D; Cc = F;     t = bid - 4096; }
    else                 { src = W2;    dst = wt + 4 * D * D + D * F; Rr = F; Cc = D;   t = bid - 8192; }
    int ntx = Cc >> 5;
    int c0 = (t % ntx) * 32, r0 = (t / ntx) * 32;
    __shared__ u16 tl[32][33];
    int x = threadIdx.x & 31, y = threadIdx.x >> 5;
#pragma unroll
    for (int i = 0; i < 4; i++)
        tl[y + i * 8][x] = f2bf(src[(size_t)(r0 + y + i * 8) * Cc + c0 + x]);
    __syncthreads();
#pragma unroll
    for (int i = 0; i < 4; i++)
        dst[(size_t)(c0 + y + i * 8) * Rr + r0 + x] = tl[x][y + i * 8];
}

// ---------------- GEMM: C[M,N] = A[M,K](bf16) @ Bt[N,K](bf16)^T + bias(f32) ----------------
// T3-minimum 2-phase: LDS double-buffer, stage(t+1) issued BEFORE ds_read+MFMA(t),
// ONE vmcnt(0)+barrier per K-step (the __syncthreads drain).
// EPI: 0 = store bf16 (VT: V cols -> vT instead), 1 = GELU->bf16, 3 = store f32,
//      4 = f32 partial at pp + blockIdx.z*2048*ldc (no bias), K = per-split K
template <int EPI, bool VT>
__global__ __launch_bounds__(256) void k_gemm_bt(
        const u16* __restrict__ A, int lda,
        const u16* __restrict__ Bt, int ldb,
        const float* __restrict__ bias,
        void* __restrict__ Cv, int ldc, int K, u16* __restrict__ vT) {
    __shared__ u16 tA[2][128 * 32];
    __shared__ u16 tB[2][128 * 32];
    // XCD-chunked bijective swizzle (m204)
    int gm = gridDim.x;
    int nwg = gm * gridDim.y;
    int orig = blockIdx.y * gm + blockIdx.x;
    int xcd = orig & 7, idx = orig >> 3;
    int q = nwg >> 3, rr = nwg & 7;
    int wg = (xcd < rr ? xcd * (q + 1) : rr * (q + 1) + (xcd - rr) * q) + idx;
    int m0 = (wg % gm) * 128, n0 = (wg / gm) * 128;
    int koff = (EPI == 4) ? blockIdx.z * K : 0;
    int tid = threadIdx.x, wave = tid >> 6, lane = tid & 63;
    int llo = lane & 15, lhi = lane >> 4;
    int wr = wave >> 1, wc = wave & 1;
    f32x4 acc[4][4] = {};
    int nk = K / 32;
    // prologue: stage K-tile 0 into buf 0; drain; barrier
    for (int c = wave; c < 8; c += 4) {
        int e = (c * 64 + lane) * 8;
        int row = e >> 5, col = e & 31;
        gl16(A  + (size_t)(m0 + row) * lda + koff + col, &tA[0][c * 512]);
        gl16(Bt + (size_t)(n0 + row) * ldb + koff + col, &tB[0][c * 512]);
    }
    __syncthreads();
    int cur = 0;
    for (int t = 0; t < nk; ++t) {
        // issue next-tile staging into buf[cur^1] BEFORE compute (stays in flight across MFMA)
        if (t + 1 < nk) {
            int kk = koff + (t + 1) * 32;
            for (int c = wave; c < 8; c += 4) {
                int e = (c * 64 + lane) * 8;
                int row = e >> 5, col = e & 31;
                gl16(A  + (size_t)(m0 + row) * lda + kk + col, &tA[cur ^ 1][c * 512]);
                gl16(Bt + (size_t)(n0 + row) * ldb + kk + col, &tB[cur ^ 1][c * 512]);
            }
        }
        bf16x8 af[4], bfr[4];
#pragma unroll
        for (int mi = 0; mi < 4; mi++) af[mi] = ld8(&tA[cur][(wr * 64 + mi * 16 + llo) * 32 + lhi * 8]);
#pragma unroll
        for (int ni = 0; ni < 4; ni++) bfr[ni] = ld8(&tB[cur][(wc * 64 + ni * 16 + llo) * 32 + lhi * 8]);
#pragma unroll
        for (int mi = 0; mi < 4; mi++)
#pragma unroll
            for (int ni = 0; ni < 4; ni++)
                acc[mi][ni] = __builtin_amdgcn_mfma_f32_16x16x32_bf16(af[mi], bfr[ni], acc[mi][ni], 0, 0, 0);
        __syncthreads();   // single vmcnt(0)+lgkmcnt(0)+barrier per K-step
        cur ^= 1;
    }
#pragma unroll
    for (int ni = 0; ni < 4; ni++) {
        int col = n0 + wc * 64 + ni * 16 + llo;
        float bb = 0.f;
        if (EPI != 4) bb = bias[col];
#pragma unroll
        for (int mi = 0; mi < 4; mi++) {
            int row0 = m0 + wr * 64 + mi * 16 + lhi * 4;
            if (VT && col >= 2 * D) {
                // write V^T: vT[b*16 + (col-2D)/64][(col-2D)&63][t], 4 consecutive t
                int dv = col - 2 * D;
                int b_ = row0 >> 10, t_ = row0 & (T - 1);
                u16x4 pk;
#pragma unroll
                for (int r = 0; r < 4; r++) pk[r] = f2bf(acc[mi][ni][r] + bb);
                *(u16x4*)(vT + ((size_t)(b_ * 16 + (dv >> 6)) * HD + (dv & 63)) * T + t_) = pk;
            } else {
#pragma unroll
                for (int r = 0; r < 4; r++) {
                    int row = row0 + r;
                    float o = acc[mi][ni][r] + bb;
                    if (EPI == 1) o = 0.5f * o * (1.f + erff(o * 0.70710678118f));
                    if (EPI == 3) {
                        ((float*)Cv)[(size_t)row * ldc + col] = o;
                    } else if (EPI == 4) {
                        ((float*)Cv)[((size_t)blockIdx.z * (B * T) + row) * ldc + col] = o;
                    } else {
                        ((u16*)Cv)[(size_t)row * ldc + col] = f2bf(o);
                    }
                }
            }
        }
    }
}

// ---------------- fused flash attention (+ optional f32 prob write for last layer) ----
// Swapped QK^T: mfma(K,Q) so lane owns q-row = i0 + (lane&15); P staged per-wave in LDS.
template <int PW>
__global__ __launch_bounds__(256) void k_fattn(const u16* __restrict__ qkv,
        const u16* __restrict__ vT, u16* __restrict__ out, float* __restrict__ attnF) {
    __shared__ u16 plds[4][16 * 40];     // per-wave 16 q-rows x 32 k, stride 40 u16
    int bh = blockIdx.y; int b = bh >> 4, h = bh & 15;
    int tid = threadIdx.x, wave = tid >> 6, lane = tid & 63;
    int llo = lane & 15, lhi = lane >> 4;
    int i0 = blockIdx.x * 64 + wave * 16;
    const u16* qb = qkv + (size_t)b * T * (3 * D) + h * HD;
    const u16* kb = qb + D;
    const u16* vt = vT + (size_t)bh * HD * T;
    bf16x8 q0 = ld8(qb + (size_t)(i0 + llo) * (3 * D) + lhi * 8);
    bf16x8 q1 = ld8(qb + (size_t)(i0 + llo) * (3 * D) + 32 + lhi * 8);
    int qrow = i0 + llo;
    float m = -3e38f, s = 0.f;           // row stats for q-row = qrow (dup across lhi)
    f32x4 oacc[4] = {};                  // O[q = lhi*4+r][d = n*16+llo]
    u16* pw = &plds[wave][0];
    for (int k0 = 0; k0 < i0 + 16; k0 += 32) {
        f32x4 sc0 = {}, sc1 = {};
        {
            bf16x8 kf0 = ld8(kb + (size_t)(k0 + llo) * (3 * D) + lhi * 8);
            bf16x8 kf1 = ld8(kb + (size_t)(k0 + llo) * (3 * D) + 32 + lhi * 8);
            sc0 = __builtin_amdgcn_mfma_f32_16x16x32_bf16(kf0, q0, sc0, 0, 0, 0);
            sc0 = __builtin_amdgcn_mfma_f32_16x16x32_bf16(kf1, q1, sc0, 0, 0, 0);
        }
        if (k0 + 16 < i0 + 16) {
            bf16x8 kf0 = ld8(kb + (size_t)(k0 + 16 + llo) * (3 * D) + lhi * 8);
            bf16x8 kf1 = ld8(kb + (size_t)(k0 + 16 + llo) * (3 * D) + 32 + lhi * 8);
            sc1 = __builtin_amdgcn_mfma_f32_16x16x32_bf16(kf0, q0, sc1, 0, 0, 0);
            sc1 = __builtin_amdgcn_mfma_f32_16x16x32_bf16(kf1, q1, sc1, 0, 0, 0);
        }
        float vv[8]; float mx = m;
#pragma unroll
        for (int hf = 0; hf < 2; hf++)
#pragma unroll
            for (int r = 0; r < 4; r++) {
                int k = k0 + hf * 16 + lhi * 4 + r;
                float x = (hf ? sc1[r] : sc0[r]) * 0.125f;
                float v = (k <= qrow) ? x : -3e38f;
                vv[hf * 4 + r] = v;
                mx = fmaxf(mx, v);
            }
        mx = fmaxf(mx, __shfl_xor(mx, 16));
        mx = fmaxf(mx, __shfl_xor(mx, 32));
        float p[8]; float ps = 0.f;
#pragma unroll
        for (int j = 0; j < 8; j++) { p[j] = __expf(vv[j] - mx); ps += p[j]; }
        ps += __shfl_xor(ps, 16);
        ps += __shfl_xor(ps, 32);
        float scale = __expf(m - mx);
        s = s * scale + ps;
        m = mx;
        float sr[4];
#pragma unroll
        for (int r = 0; r < 4; r++) sr[r] = __shfl(scale, lhi * 4 + r);
#pragma unroll
        for (int n = 0; n < 4; n++)
#pragma unroll
            for (int r = 0; r < 4; r++) oacc[n][r] *= sr[r];
#pragma unroll
        for (int hf = 0; hf < 2; hf++) {
            u16x4 pk;
#pragma unroll
            for (int r = 0; r < 4; r++) pk[r] = f2bf(p[hf * 4 + r]);
            *(u16x4*)(pw + llo * 40 + hf * 16 + lhi * 4) = pk;
        }
        bf16x8 pa = ld8(pw + llo * 40 + lhi * 8);
#pragma unroll
        for (int n = 0; n < 4; n++) {
            bf16x8 vb = ld8(vt + (size_t)(n * 16 + llo) * T + k0 + lhi * 8);
            oacc[n] = __builtin_amdgcn_mfma_f32_16x16x32_bf16(pa, vb, oacc[n], 0, 0, 0);
        }
    }
    float inv = 1.f / s;
    float ir[4];
#pragma unroll
    for (int r = 0; r < 4; r++) ir[r] = __shfl(inv, lhi * 4 + r);
#pragma unroll
    for (int n = 0; n < 4; n++)
#pragma unroll
        for (int r = 0; r < 4; r++) {
            int i = i0 + lhi * 4 + r, c = n * 16 + llo;
            out[(size_t)(b * T + i) * D + h * HD + c] = f2bf(oacc[n][r] * ir[r]);
        }
    if (PW) {
        // second sweep: write f32 probs for q-row = qrow over all j (zeros above diagonal)
        float* ar = attnF + ((size_t)bh * T + qrow) * T;
        for (int j0 = 0; j0 < T; j0 += 16) {
            f32x4 pv = {};
            if (j0 <= qrow) {
                if (j0 < i0 + 16) {
                    bf16x8 kf0 = ld8(kb + (size_t)(j0 + llo) * (3 * D) + lhi * 8);
                    bf16x8 kf1 = ld8(kb + (size_t)(j0 + llo) * (3 * D) + 32 + lhi * 8);
                    f32x4 sc = {};
                    sc = __builtin_amdgcn_mfma_f32_16x16x32_bf16(kf0, q0, sc, 0, 0, 0);
                    sc = __builtin_amdgcn_mfma_f32_16x16x32_bf16(kf1, q1, sc, 0, 0, 0);
#pragma unroll
                    for (int r = 0; r < 4; r++) {
                        int j = j0 + lhi * 4 + r;
                        pv[r] = (j <= qrow) ? __expf(sc[r] * 0.125f - m) * inv : 0.f;
                    }
                }
            }
            *(f32x4*)(ar + j0 + lhi * 4) = pv;
        }
    }
}

extern "C" void kernel_launch(void* const* d_in, const int* in_sizes, int n_in,
                              void* d_out, int out_size, void* d_ws, size_t ws_size,
                              hipStream_t stream) {
    const int*   tok   = (const int*)d_in[0];
    const float* emb   = (const float*)d_in[2];
    const float* pe    = (const float*)d_in[3];
    const float* ln1g  = (const float*)d_in[4];
    const float* ln1b  = (const float*)d_in[5];
    const float* Wqkv  = (const float*)d_in[6];
    const float* bqkv  = (const float*)d_in[7];
    const float* Wproj = (const float*)d_in[8];
    const float* bproj = (const float*)d_in[9];
    const float* ln2g  = (const float*)d_in[10];
    const float* ln2b  = (const float*)d_in[11];
    const float* W1    = (const float*)d_in[12];
    const float* b1    = (const float*)d_in[13];
    const float* W2    = (const float*)d_in[14];
    const float* b2    = (const float*)d_in[15];
    const float* lnfg  = (const float*)d_in[16];
    const float* lnfb  = (const float*)d_in[17];
    const float* outb  = (const float*)d_in[18];

    float* logits  = (float*)d_out;                    // [B*T, V] f32
    float* attnF   = logits + (size_t)B * T * V;       // [B*H, T, T] f32

    char* w = (char*)d_ws;
    float* x    = (float*)w;  w += (size_t)B * T * D * 4;       // 8.39 MB
    u16* lnout  = (u16*)w;    w += (size_t)B * T * D * 2;       // 4.19 MB
    u16* qkv    = (u16*)w;    w += (size_t)B * T * 3 * D * 2;   // 12.58 MB
    u16* vT     = (u16*)w;    w += (size_t)B * H * HD * T * 2;  // 4.19 MB
    u16* aout   = (u16*)w;    w += (size_t)B * T * D * 2;       // 4.19 MB
    char* tail = w;
    u16* hmid   = (u16*)w;    w += (size_t)B * T * F * 2;       // 16.78 MB
    u16* WTL    = (u16*)w;    w += (size_t)(5 * D * D + 2 * D * F) * 2; // 25.17 MB
    float* pp   = (float*)w;  w += (size_t)4 * B * T * D * 4;   // 33.55 MB (splitK partials)
    u16* embB   = (u16*)tail;                                   // 65.54 MB, aliases hmid+WTL+pp

    dim3 blk(256);
    k_embln<<<dim3(B * T), blk, 0, stream>>>(tok, emb, pe, ln1g, ln1b, x, lnout);

    for (int l = 0; l < L; l++) {
        k_castT4<<<dim3(12288), blk, 0, stream>>>(
            Wqkv + (size_t)l * D * 3 * D, Wproj + (size_t)l * D * D,
            W1 + (size_t)l * D * F, W2 + (size_t)l * F * D, WTL);
        k_gemm_bt<0, true><<<dim3(B * T / 128, 3 * D / 128), blk, 0, stream>>>(
            lnout, D, WTL, D, bqkv + l * 3 * D, qkv, 3 * D, D, vT);
        if (l == L - 1)
            k_fattn<1><<<dim3(T / 64, B * H), blk, 0, stream>>>(qkv, vT, aout, attnF);
        else
            k_fattn<0><<<dim3(T / 64, B * H), blk, 0, stream>>>(qkv, vT, aout, attnF);
        k_gemm_bt<4, false><<<dim3(B * T / 128, D / 128, 2), blk, 0, stream>>>(
            aout, D, WTL + (size_t)3 * D * D, D, nullptr, pp, D, D / 2, nullptr);
        k_redln<2><<<dim3(B * T), blk, 0, stream>>>(pp, bproj + l * D, x,
            ln2g + l * D, ln2b + l * D, lnout);
        k_gemm_bt<1, false><<<dim3(B * T / 128, F / 128), blk, 0, stream>>>(
            lnout, D, WTL + (size_t)4 * D * D, D, b1 + l * F, hmid, F, D, nullptr);
        k_gemm_bt<4, false><<<dim3(B * T / 128, D / 128, 4), blk, 0, stream>>>(
            hmid, F, WTL + (size_t)4 * D * D + D * F, F, nullptr, pp, D, F / 4, nullptr);
        const float* ng = (l == L - 1) ? lnfg : ln1g + (l + 1) * D;
        const float* nb = (l == L - 1) ? lnfb : ln1b + (l + 1) * D;
        k_redln<4><<<dim3(B * T), blk, 0, stream>>>(pp, b2 + l * D, x, ng, nb, lnout);
    }
    k_cast<<<dim3(V * D / 1024), blk, 0, stream>>>(emb, embB);
    k_gemm_bt<3, false><<<dim3(B * T / 128, V / 128), blk, 0, stream>>>(
        lnout, D, embB, D, outb, logits, V, D, nullptr);
}

// Round 7
// 1069.408 us; speedup vs baseline: 1.4676x; 1.0295x over previous
//
#include <hip/hip_runtime.h>
#include <cstdint>

#define DEV static __device__ __forceinline__

typedef unsigned short u16;
typedef __bf16 bf16x8 __attribute__((ext_vector_type(8)));
typedef float f32x4 __attribute__((ext_vector_type(4)));
typedef unsigned short u16x4 __attribute__((ext_vector_type(4)));

constexpr int V = 32000, D = 1024, H = 16, L = 4, F = 4096, T = 1024, B = 2;
constexpr int HD = 64;

DEV u16 f2bf(float f) {
    union { float f; uint32_t i; } c; c.f = f;
    uint32_t x = c.i;
    return (u16)((x + 0x7fffu + ((x >> 16) & 1u)) >> 16);
}
DEV bf16x8 ld8(const u16* p) { return *reinterpret_cast<const bf16x8*>(p); }

DEV void gl16(const void* g, void* l) {
    __builtin_amdgcn_global_load_lds((const __attribute__((address_space(1))) void*)g,
                                     (__attribute__((address_space(3))) void*)l, 16, 0, 0);
}

// ---------------- embedding + ln1(layer0) ----------------
__global__ __launch_bounds__(256) void k_embln(const int* __restrict__ tok,
        const float* __restrict__ emb, const float* __restrict__ pe,
        const float* __restrict__ g, const float* __restrict__ b,
        float* __restrict__ x, u16* __restrict__ out) {
    int row = blockIdx.x, tid = threadIdx.x;
    int t = row & (T - 1);
    int vv = tok[row];
    f32x4 v = ((const f32x4*)(emb + (size_t)vv * D))[tid] + ((const f32x4*)(pe + (size_t)t * D))[tid];
    ((f32x4*)(x + (size_t)row * D))[tid] = v;
    float s = v[0] + v[1] + v[2] + v[3];
    float s2 = v[0]*v[0] + v[1]*v[1] + v[2]*v[2] + v[3]*v[3];
#pragma unroll
    for (int m = 1; m < 64; m <<= 1) { s += __shfl_xor(s, m); s2 += __shfl_xor(s2, m); }
    __shared__ float ps[4], ps2[4];
    int wave = tid >> 6;
    if ((tid & 63) == 0) { ps[wave] = s; ps2[wave] = s2; }
    __syncthreads();
    s = ps[0] + ps[1] + ps[2] + ps[3];
    s2 = ps2[0] + ps2[1] + ps2[2] + ps2[3];
    float mean = s * (1.f / D);
    float var = s2 * (1.f / D) - mean * mean;
    float r = rsqrtf(var + 1e-5f);
    f32x4 gg = ((const f32x4*)g)[tid];
    f32x4 bb = ((const f32x4*)b)[tid];
    u16x4 o;
#pragma unroll
    for (int j = 0; j < 4; j++) o[j] = f2bf((v[j] - mean) * r * gg[j] + bb[j]);
    ((u16x4*)(out + (size_t)row * D))[tid] = o;
}

// ---------------- splitK reduce + bias + residual + LayerNorm ----------------
template <int S>
__global__ __launch_bounds__(256) void k_redln(const float* __restrict__ pp,
        const float* __restrict__ bias, float* __restrict__ x,
        const float* __restrict__ g, const float* __restrict__ b,
        u16* __restrict__ out) {
    int row = blockIdx.x, tid = threadIdx.x;
    f32x4 v = ((const f32x4*)(x + (size_t)row * D))[tid];
#pragma unroll
    for (int s = 0; s < S; s++)
        v += ((const f32x4*)(pp + ((size_t)s * (B * T) + row) * D))[tid];
    v += ((const f32x4*)bias)[tid];
    ((f32x4*)(x + (size_t)row * D))[tid] = v;
    float s = v[0] + v[1] + v[2] + v[3];
    float s2 = v[0]*v[0] + v[1]*v[1] + v[2]*v[2] + v[3]*v[3];
#pragma unroll
    for (int m = 1; m < 64; m <<= 1) { s += __shfl_xor(s, m); s2 += __shfl_xor(s2, m); }
    __shared__ float ps[4], ps2[4];
    int wave = tid >> 6;
    if ((tid & 63) == 0) { ps[wave] = s; ps2[wave] = s2; }
    __syncthreads();
    s = ps[0] + ps[1] + ps[2] + ps[3];
    s2 = ps2[0] + ps2[1] + ps2[2] + ps2[3];
    float mean = s * (1.f / D);
    float var = s2 * (1.f / D) - mean * mean;
    float r = rsqrtf(var + 1e-5f);
    f32x4 gg = ((const f32x4*)g)[tid];
    f32x4 bb = ((const f32x4*)b)[tid];
    u16x4 o;
#pragma unroll
    for (int j = 0; j < 4; j++) o[j] = f2bf((v[j] - mean) * r * gg[j] + bb[j]);
    ((u16x4*)(out + (size_t)row * D))[tid] = o;
}

// ---------------- elementwise cast f32 -> bf16 ----------------
__global__ __launch_bounds__(256) void k_cast(const float* __restrict__ src,
        u16* __restrict__ dst) {
    int i = (blockIdx.x * 256 + threadIdx.x) * 4;
    f32x4 v = *(const f32x4*)(src + i);
    u16x4 o;
#pragma unroll
    for (int j = 0; j < 4; j++) o[j] = f2bf(v[j]);
    *(u16x4*)(dst + i) = o;
}

// ---------------- batched transpose+cast of one layer's 4 weights ----------------
__global__ __launch_bounds__(256) void k_castT4(const float* __restrict__ Wqkv,
        const float* __restrict__ Wproj, const float* __restrict__ W1,
        const float* __restrict__ W2, u16* __restrict__ wt) {
    int bid = blockIdx.x;
    const float* src; u16* dst; int Rr, Cc, t;
    if (bid < 3072)      { src = Wqkv;  dst = wt;                   Rr = D; Cc = 3 * D; t = bid; }
    else if (bid < 4096) { src = Wproj; dst = wt + 3 * D * D;       Rr = D; Cc = D;     t = bid - 3072; }
    else if (bid < 8192) { src = W1;    dst = wt + 4 * D * D;       Rr = D; Cc = F;     t = bid - 4096; }
    else                 { src = W2;    dst = wt + 4 * D * D + D * F; Rr = F; Cc = D;   t = bid - 8192; }
    int ntx = Cc >> 5;
    int c0 = (t % ntx) * 32, r0 = (t / ntx) * 32;
    __shared__ u16 tl[32][33];
    int x = threadIdx.x & 31, y = threadIdx.x >> 5;
#pragma unroll
    for (int i = 0; i < 4; i++)
        tl[y + i * 8][x] = f2bf(src[(size_t)(r0 + y + i * 8) * Cc + c0 + x]);
    __syncthreads();
#pragma unroll
    for (int i = 0; i < 4; i++)
        dst[(size_t)(c0 + y + i * 8) * Rr + r0 + x] = tl[x][y + i * 8];
}

// ---------------- 128-tile GEMM (2-phase dbuf), EPI as before ----------------
template <int EPI, bool VT>
__global__ __launch_bounds__(256) void k_gemm_bt(
        const u16* __restrict__ A, int lda,
        const u16* __restrict__ Bt, int ldb,
        const float* __restrict__ bias,
        void* __restrict__ Cv, int ldc, int K, u16* __restrict__ vT) {
    __shared__ u16 tA[2][128 * 32];
    __shared__ u16 tB[2][128 * 32];
    int gm = gridDim.x;
    int nwg = gm * gridDim.y;
    int orig = blockIdx.y * gm + blockIdx.x;
    int xcd = orig & 7, idx = orig >> 3;
    int q = nwg >> 3, rr = nwg & 7;
    int wg = (xcd < rr ? xcd * (q + 1) : rr * (q + 1) + (xcd - rr) * q) + idx;
    int m0 = (wg % gm) * 128, n0 = (wg / gm) * 128;
    int koff = (EPI == 4) ? blockIdx.z * K : 0;
    int tid = threadIdx.x, wave = tid >> 6, lane = tid & 63;
    int llo = lane & 15, lhi = lane >> 4;
    int wr = wave >> 1, wc = wave & 1;
    f32x4 acc[4][4] = {};
    int nk = K / 32;
    for (int c = wave; c < 8; c += 4) {
        int e = (c * 64 + lane) * 8;
        int row = e >> 5, col = e & 31;
        gl16(A  + (size_t)(m0 + row) * lda + koff + col, &tA[0][c * 512]);
        gl16(Bt + (size_t)(n0 + row) * ldb + koff + col, &tB[0][c * 512]);
    }
    __syncthreads();
    int cur = 0;
    for (int t = 0; t < nk; ++t) {
        if (t + 1 < nk) {
            int kk = koff + (t + 1) * 32;
            for (int c = wave; c < 8; c += 4) {
                int e = (c * 64 + lane) * 8;
                int row = e >> 5, col = e & 31;
                gl16(A  + (size_t)(m0 + row) * lda + kk + col, &tA[cur ^ 1][c * 512]);
                gl16(Bt + (size_t)(n0 + row) * ldb + kk + col, &tB[cur ^ 1][c * 512]);
            }
        }
        bf16x8 af[4], bfr[4];
#pragma unroll
        for (int mi = 0; mi < 4; mi++) af[mi] = ld8(&tA[cur][(wr * 64 + mi * 16 + llo) * 32 + lhi * 8]);
#pragma unroll
        for (int ni = 0; ni < 4; ni++) bfr[ni] = ld8(&tB[cur][(wc * 64 + ni * 16 + llo) * 32 + lhi * 8]);
#pragma unroll
        for (int mi = 0; mi < 4; mi++)
#pragma unroll
            for (int ni = 0; ni < 4; ni++)
                acc[mi][ni] = __builtin_amdgcn_mfma_f32_16x16x32_bf16(af[mi], bfr[ni], acc[mi][ni], 0, 0, 0);
        __syncthreads();
        cur ^= 1;
    }
#pragma unroll
    for (int ni = 0; ni < 4; ni++) {
        int col = n0 + wc * 64 + ni * 16 + llo;
        float bb = 0.f;
        if (EPI != 4) bb = bias[col];
#pragma unroll
        for (int mi = 0; mi < 4; mi++) {
            int row0 = m0 + wr * 64 + mi * 16 + lhi * 4;
            if (VT && col >= 2 * D) {
                int dv = col - 2 * D;
                int b_ = row0 >> 10, t_ = row0 & (T - 1);
                u16x4 pk;
#pragma unroll
                for (int r = 0; r < 4; r++) pk[r] = f2bf(acc[mi][ni][r] + bb);
                *(u16x4*)(vT + ((size_t)(b_ * 16 + (dv >> 6)) * HD + (dv & 63)) * T + t_) = pk;
            } else {
#pragma unroll
                for (int r = 0; r < 4; r++) {
                    int row = row0 + r;
                    float o = acc[mi][ni][r] + bb;
                    if (EPI == 1) o = 0.5f * o * (1.f + erff(o * 0.70710678118f));
                    if (EPI == 3) {
                        ((float*)Cv)[(size_t)row * ldc + col] = o;
                    } else if (EPI == 4) {
                        ((float*)Cv)[((size_t)blockIdx.z * (B * T) + row) * ldc + col] = o;
                    } else {
                        ((u16*)Cv)[(size_t)row * ldc + col] = f2bf(o);
                    }
                }
            }
        }
    }
}

// ---------------- 256x256 BK=64 counted-vmcnt pipelined GEMM (f32 out + bias) ----------
// 8 waves (2M x 4N), per-wave C = 128x64. LDS 128 KiB: [buf][Ak0,Bk0,Ak1,Bk1][256r][32k].
// Per K-tile: 4 phases {ds_read ; stage 1 half (2 gl16) ; 16 MFMA ; sched_barrier ; s_barrier}.
// Swizzle: byte ^= ((byte>>9)&1)<<5, inverse-applied on gl16 source (rule #21).
DEV bf16x8 ldf(const u16* half, int row, int lhi) {
    int lb = row * 64 + lhi * 16;
    lb ^= ((lb >> 9) & 1) << 5;
    return *(const bf16x8*)((const char*)half + lb);
}
DEV void stg(const u16* gb, int ld, int kc, u16* dstBase, int wave, int lane) {
#pragma unroll
    for (int i = 0; i < 2; i++) {
        int p = (wave * 2 + i) * 64 + lane;
        int l = p ^ (((p >> 5) & 1) << 1);
        gl16(gb + (size_t)(l >> 2) * ld + kc + (l & 3) * 8, dstBase + (wave * 2 + i) * 512);
    }
}
#define SB_BAR() do { __builtin_amdgcn_sched_barrier(0); __builtin_amdgcn_s_barrier(); } while (0)

__global__ __launch_bounds__(512, 2) void k_gemm8(
        const u16* __restrict__ A, int lda,
        const u16* __restrict__ Bt, int ldb,
        const float* __restrict__ bias,
        float* __restrict__ C, int ldc, int K) {
    __shared__ u16 lds[2][4][256 * 32];
    int gm = gridDim.x, nwg = gm * gridDim.y;
    int orig = blockIdx.y * gm + blockIdx.x;
    int xcd = orig & 7, idx = orig >> 3;
    int q = nwg >> 3, rr = nwg & 7;
    int wg = (xcd < rr ? xcd * (q + 1) : rr * (q + 1) + (xcd - rr) * q) + idx;
    int m0 = (wg % gm) * 256, n0 = (wg / gm) * 256;
    int tid = threadIdx.x, wave = tid >> 6, lane = tid & 63;
    int llo = lane & 15, lhi = lane >> 4;
    int wm = wave >> 2, wn = wave & 3;
    const u16* Ab = A + (size_t)m0 * lda;
    const u16* Bb = Bt + (size_t)n0 * ldb;
    int nk = K >> 6;
    f32x4 acc[8][4] = {};
    // prologue = virtual iters -2/-1: KT0 all 4 halves, KT1 first 3
    stg(Ab, lda, 0,   &lds[0][0][0], wave, lane);
    stg(Bb, ldb, 0,   &lds[0][1][0], wave, lane);
    stg(Ab, lda, 32,  &lds[0][2][0], wave, lane);
    stg(Bb, ldb, 32,  &lds[0][3][0], wave, lane);
    stg(Ab, lda, 64,  &lds[1][0][0], wave, lane);
    stg(Bb, ldb, 64,  &lds[1][1][0], wave, lane);
    stg(Ab, lda, 96,  &lds[1][2][0], wave, lane);
    asm volatile("s_waitcnt vmcnt(10)");
    SB_BAR();
    for (int t = 0; t < nk; ++t) {
        const int bf = t & 1;
        bf16x8 af[8], b0, b1;
        // ---- phase 1: ks0, n0-1; stage Bk1(t+1) ----
#pragma unroll
        for (int mi = 0; mi < 8; mi++) af[mi] = ldf(&lds[bf][0][0], wm * 128 + mi * 16 + llo, lhi);
        b0 = ldf(&lds[bf][1][0], wn * 64 + llo, lhi);
        b1 = ldf(&lds[bf][1][0], wn * 64 + 16 + llo, lhi);
        if (t + 1 < nk) stg(Bb, ldb, (t + 1) * 64 + 32, &lds[bf ^ 1][3][0], wave, lane);
        __builtin_amdgcn_s_setprio(1);
#pragma unroll
        for (int mi = 0; mi < 8; mi++) {
            acc[mi][0] = __builtin_amdgcn_mfma_f32_16x16x32_bf16(af[mi], b0, acc[mi][0], 0, 0, 0);
            acc[mi][1] = __builtin_amdgcn_mfma_f32_16x16x32_bf16(af[mi], b1, acc[mi][1], 0, 0, 0);
        }
        __builtin_amdgcn_s_setprio(0);
        SB_BAR();
        // ---- phase 2: ks0, n2-3; stage Ak0(t+2); vmcnt gate for ph3 reads ----
        b0 = ldf(&lds[bf][1][0], wn * 64 + 32 + llo, lhi);
        b1 = ldf(&lds[bf][1][0], wn * 64 + 48 + llo, lhi);
        if (t + 2 < nk) stg(Ab, lda, (t + 2) * 64, &lds[bf][0][0], wave, lane);
        __builtin_amdgcn_s_setprio(1);
#pragma unroll
        for (int mi = 0; mi < 8; mi++) {
            acc[mi][2] = __builtin_amdgcn_mfma_f32_16x16x32_bf16(af[mi], b0, acc[mi][2], 0, 0, 0);
            acc[mi][3] = __builtin_amdgcn_mfma_f32_16x16x32_bf16(af[mi], b1, acc[mi][3], 0, 0, 0);
        }
        __builtin_amdgcn_s_setprio(0);
        if (t + 2 < nk)      { asm volatile("s_waitcnt vmcnt(10)"); }
        else if (t + 1 < nk) { asm volatile("s_waitcnt vmcnt(8)"); }
        else                 { asm volatile("s_waitcnt vmcnt(0)"); }
        SB_BAR();
        // ---- phase 3: ks1, n0-1; stage Bk0(t+2) ----
#pragma unroll
        for (int mi = 0; mi < 8; mi++) af[mi] = ldf(&lds[bf][2][0], wm * 128 + mi * 16 + llo, lhi);
        b0 = ldf(&lds[bf][3][0], wn * 64 + llo, lhi);
        b1 = ldf(&lds[bf][3][0], wn * 64 + 16 + llo, lhi);
        if (t + 2 < nk) stg(Bb, ldb, (t + 2) * 64, &lds[bf][1][0], wave, lane);
        __builtin_amdgcn_s_setprio(1);
#pragma unroll
        for (int mi = 0; mi < 8; mi++) {
            acc[mi][0] = __builtin_amdgcn_mfma_f32_16x16x32_bf16(af[mi], b0, acc[mi][0], 0, 0, 0);
            acc[mi][1] = __builtin_amdgcn_mfma_f32_16x16x32_bf16(af[mi], b1, acc[mi][1], 0, 0, 0);
        }
        __builtin_amdgcn_s_setprio(0);
        SB_BAR();
        // ---- phase 4: ks1, n2-3; stage Ak1(t+2); vmcnt gate for next ph1 reads ----
        b0 = ldf(&lds[bf][3][0], wn * 64 + 32 + llo, lhi);
        b1 = ldf(&lds[bf][3][0], wn * 64 + 48 + llo, lhi);
        if (t + 2 < nk) stg(Ab, lda, (t + 2) * 64 + 32, &lds[bf][2][0], wave, lane);
        __builtin_amdgcn_s_setprio(1);
#pragma unroll
        for (int mi = 0; mi < 8; mi++) {
            acc[mi][2] = __builtin_amdgcn_mfma_f32_16x16x32_bf16(af[mi], b0, acc[mi][2], 0, 0, 0);
            acc[mi][3] = __builtin_amdgcn_mfma_f32_16x16x32_bf16(af[mi], b1, acc[mi][3], 0, 0, 0);
        }
        __builtin_amdgcn_s_setprio(0);
        if (t + 1 < nk) {
            if (t + 2 < nk) { asm volatile("s_waitcnt vmcnt(10)"); }
            else            { asm volatile("s_waitcnt vmcnt(4)"); }
        }
        SB_BAR();
    }
#pragma unroll
    for (int ni = 0; ni < 4; ni++) {
        int col = n0 + wn * 64 + ni * 16 + llo;
        float bb = bias[col];
#pragma unroll
        for (int mi = 0; mi < 8; mi++) {
            int row0 = m0 + wm * 128 + mi * 16 + lhi * 4;
#pragma unroll
            for (int r = 0; r < 4; r++)
                C[(size_t)(row0 + r) * ldc + col] = acc[mi][ni][r] + bb;
        }
    }
}

// ---------------- fused flash attention (+ optional f32 prob write) ----------------
template <int PW>
__global__ __launch_bounds__(256) void k_fattn(const u16* __restrict__ qkv,
        const u16* __restrict__ vT, u16* __restrict__ out, float* __restrict__ attnF) {
    __shared__ u16 plds[4][16 * 40];
    int bh = blockIdx.y; int b = bh >> 4, h = bh & 15;
    int tid = threadIdx.x, wave = tid >> 6, lane = tid & 63;
    int llo = lane & 15, lhi = lane >> 4;
    int i0 = blockIdx.x * 64 + wave * 16;
    const u16* qb = qkv + (size_t)b * T * (3 * D) + h * HD;
    const u16* kb = qb + D;
    const u16* vt = vT + (size_t)bh * HD * T;
    bf16x8 q0 = ld8(qb + (size_t)(i0 + llo) * (3 * D) + lhi * 8);
    bf16x8 q1 = ld8(qb + (size_t)(i0 + llo) * (3 * D) + 32 + lhi * 8);
    int qrow = i0 + llo;
    float m = -3e38f, s = 0.f;
    f32x4 oacc[4] = {};
    u16* pw = &plds[wave][0];
    for (int k0 = 0; k0 < i0 + 16; k0 += 32) {
        f32x4 sc0 = {}, sc1 = {};
        {
            bf16x8 kf0 = ld8(kb + (size_t)(k0 + llo) * (3 * D) + lhi * 8);
            bf16x8 kf1 = ld8(kb + (size_t)(k0 + llo) * (3 * D) + 32 + lhi * 8);
            sc0 = __builtin_amdgcn_mfma_f32_16x16x32_bf16(kf0, q0, sc0, 0, 0, 0);
            sc0 = __builtin_amdgcn_mfma_f32_16x16x32_bf16(kf1, q1, sc0, 0, 0, 0);
        }
        if (k0 + 16 < i0 + 16) {
            bf16x8 kf0 = ld8(kb + (size_t)(k0 + 16 + llo) * (3 * D) + lhi * 8);
            bf16x8 kf1 = ld8(kb + (size_t)(k0 + 16 + llo) * (3 * D) + 32 + lhi * 8);
            sc1 = __builtin_amdgcn_mfma_f32_16x16x32_bf16(kf0, q0, sc1, 0, 0, 0);
            sc1 = __builtin_amdgcn_mfma_f32_16x16x32_bf16(kf1, q1, sc1, 0, 0, 0);
        }
        float vv[8]; float mx = m;
#pragma unroll
        for (int hf = 0; hf < 2; hf++)
#pragma unroll
            for (int r = 0; r < 4; r++) {
                int k = k0 + hf * 16 + lhi * 4 + r;
                float x = (hf ? sc1[r] : sc0[r]) * 0.125f;
                float v = (k <= qrow) ? x : -3e38f;
                vv[hf * 4 + r] = v;
                mx = fmaxf(mx, v);
            }
        mx = fmaxf(mx, __shfl_xor(mx, 16));
        mx = fmaxf(mx, __shfl_xor(mx, 32));
        float p[8]; float ps = 0.f;
#pragma unroll
        for (int j = 0; j < 8; j++) { p[j] = __expf(vv[j] - mx); ps += p[j]; }
        ps += __shfl_xor(ps, 16);
        ps += __shfl_xor(ps, 32);
        float scale = __expf(m - mx);
        s = s * scale + ps;
        m = mx;
        float sr[4];
#pragma unroll
        for (int r = 0; r < 4; r++) sr[r] = __shfl(scale, lhi * 4 + r);
#pragma unroll
        for (int n = 0; n < 4; n++)
#pragma unroll
            for (int r = 0; r < 4; r++) oacc[n][r] *= sr[r];
#pragma unroll
        for (int hf = 0; hf < 2; hf++) {
            u16x4 pk;
#pragma unroll
            for (int r = 0; r < 4; r++) pk[r] = f2bf(p[hf * 4 + r]);
            *(u16x4*)(pw + llo * 40 + hf * 16 + lhi * 4) = pk;
        }
        bf16x8 pa = ld8(pw + llo * 40 + lhi * 8);
#pragma unroll
        for (int n = 0; n < 4; n++) {
            bf16x8 vb = ld8(vt + (size_t)(n * 16 + llo) * T + k0 + lhi * 8);
            oacc[n] = __builtin_amdgcn_mfma_f32_16x16x32_bf16(pa, vb, oacc[n], 0, 0, 0);
        }
    }
    float inv = 1.f / s;
    float ir[4];
#pragma unroll
    for (int r = 0; r < 4; r++) ir[r] = __shfl(inv, lhi * 4 + r);
#pragma unroll
    for (int n = 0; n < 4; n++)
#pragma unroll
        for (int r = 0; r < 4; r++) {
            int i = i0 + lhi * 4 + r, c = n * 16 + llo;
            out[(size_t)(b * T + i) * D + h * HD + c] = f2bf(oacc[n][r] * ir[r]);
        }
    if (PW) {
        float* ar = attnF + ((size_t)bh * T + qrow) * T;
        for (int j0 = 0; j0 < T; j0 += 16) {
            f32x4 pv = {};
            if (j0 <= qrow) {
                if (j0 < i0 + 16) {
                    bf16x8 kf0 = ld8(kb + (size_t)(j0 + llo) * (3 * D) + lhi * 8);
                    bf16x8 kf1 = ld8(kb + (size_t)(j0 + llo) * (3 * D) + 32 + lhi * 8);
                    f32x4 sc = {};
                    sc = __builtin_amdgcn_mfma_f32_16x16x32_bf16(kf0, q0, sc, 0, 0, 0);
                    sc = __builtin_amdgcn_mfma_f32_16x16x32_bf16(kf1, q1, sc, 0, 0, 0);
#pragma unroll
                    for (int r = 0; r < 4; r++) {
                        int j = j0 + lhi * 4 + r;
                        pv[r] = (j <= qrow) ? __expf(sc[r] * 0.125f - m) * inv : 0.f;
                    }
                }
            }
            *(f32x4*)(ar + j0 + lhi * 4) = pv;
        }
    }
}

extern "C" void kernel_launch(void* const* d_in, const int* in_sizes, int n_in,
                              void* d_out, int out_size, void* d_ws, size_t ws_size,
                              hipStream_t stream) {
    const int*   tok   = (const int*)d_in[0];
    const float* emb   = (const float*)d_in[2];
    const float* pe    = (const float*)d_in[3];
    const float* ln1g  = (const float*)d_in[4];
    const float* ln1b  = (const float*)d_in[5];
    const float* Wqkv  = (const float*)d_in[6];
    const float* bqkv  = (const float*)d_in[7];
    const float* Wproj = (const float*)d_in[8];
    const float* bproj = (const float*)d_in[9];
    const float* ln2g  = (const float*)d_in[10];
    const float* ln2b  = (const float*)d_in[11];
    const float* W1    = (const float*)d_in[12];
    const float* b1    = (const float*)d_in[13];
    const float* W2    = (const float*)d_in[14];
    const float* b2    = (const float*)d_in[15];
    const float* lnfg  = (const float*)d_in[16];
    const float* lnfb  = (const float*)d_in[17];
    const float* outb  = (const float*)d_in[18];

    float* logits  = (float*)d_out;
    float* attnF   = logits + (size_t)B * T * V;

    char* w = (char*)d_ws;
    float* x    = (float*)w;  w += (size_t)B * T * D * 4;
    u16* lnout  = (u16*)w;    w += (size_t)B * T * D * 2;
    u16* qkv    = (u16*)w;    w += (size_t)B * T * 3 * D * 2;
    u16* vT     = (u16*)w;    w += (size_t)B * H * HD * T * 2;
    u16* aout   = (u16*)w;    w += (size_t)B * T * D * 2;
    char* tail = w;
    u16* hmid   = (u16*)w;    w += (size_t)B * T * F * 2;
    u16* WTL    = (u16*)w;    w += (size_t)(5 * D * D + 2 * D * F) * 2;
    float* pp   = (float*)w;  w += (size_t)4 * B * T * D * 4;
    u16* embB   = (u16*)tail;

    dim3 blk(256);
    k_embln<<<dim3(B * T), blk, 0, stream>>>(tok, emb, pe, ln1g, ln1b, x, lnout);

    for (int l = 0; l < L; l++) {
        k_castT4<<<dim3(12288), blk, 0, stream>>>(
            Wqkv + (size_t)l * D * 3 * D, Wproj + (size_t)l * D * D,
            W1 + (size_t)l * D * F, W2 + (size_t)l * F * D, WTL);
        k_gemm_bt<0, true><<<dim3(B * T / 128, 3 * D / 128), blk, 0, stream>>>(
            lnout, D, WTL, D, bqkv + l * 3 * D, qkv, 3 * D, D, vT);
        if (l == L - 1)
            k_fattn<1><<<dim3(T / 64, B * H), blk, 0, stream>>>(qkv, vT, aout, attnF);
        else
            k_fattn<0><<<dim3(T / 64, B * H), blk, 0, stream>>>(qkv, vT, aout, attnF);
        k_gemm_bt<4, false><<<dim3(B * T / 128, D / 128, 2), blk, 0, stream>>>(
            aout, D, WTL + (size_t)3 * D * D, D, nullptr, pp, D, D / 2, nullptr);
        k_redln<2><<<dim3(B * T), blk, 0, stream>>>(pp, bproj + l * D, x,
            ln2g + l * D, ln2b + l * D, lnout);
        k_gemm_bt<1, false><<<dim3(B * T / 128, F / 128), blk, 0, stream>>>(
            lnout, D, WTL + (size_t)4 * D * D, D, b1 + l * F, hmid, F, D, nullptr);
        k_gemm_bt<4, false><<<dim3(B * T / 128, D / 128, 4), blk, 0, stream>>>(
            hmid, F, WTL + (size_t)4 * D * D + D * F, F, nullptr, pp, D, F / 4, nullptr);
        const float* ng = (l == L - 1) ? lnfg : ln1g + (l + 1) * D;
        const float* nb = (l == L - 1) ? lnfb : ln1b + (l + 1) * D;
        k_redln<4><<<dim3(B * T), blk, 0, stream>>>(pp, b2 + l * D, x, ng, nb, lnout);
    }
    k_cast<<<dim3(V * D / 1024), blk, 0, stream>>>(emb, embB);
    // logits: 256^2 pipelined GEMM, grid 8 x 125 = 1000 blocks
    k_gemm8<<<dim3(B * T / 256, V / 256), dim3(512), 0, stream>>>(
        lnout, D, embB, D, outb, logits, V, D);
}

// Round 8
// 996.242 us; speedup vs baseline: 1.5754x; 1.0734x over previous
//
#include <hip/hip_runtime.h>
#include <cstdint>

#define DEV static __device__ __forceinline__

typedef unsigned short u16;
typedef __bf16 bf16x8 __attribute__((ext_vector_type(8)));
typedef float f32x4 __attribute__((ext_vector_type(4)));
typedef unsigned short u16x4 __attribute__((ext_vector_type(4)));

constexpr int V = 32000, D = 1024, H = 16, L = 4, F = 4096, T = 1024, B = 2;
constexpr int HD = 64;

DEV u16 f2bf(float f) {
    union { float f; uint32_t i; } c; c.f = f;
    uint32_t x = c.i;
    return (u16)((x + 0x7fffu + ((x >> 16) & 1u)) >> 16);
}
DEV bf16x8 ld8(const u16* p) { return *reinterpret_cast<const bf16x8*>(p); }

DEV void gl16(const void* g, void* l) {
    __builtin_amdgcn_global_load_lds((const __attribute__((address_space(1))) void*)g,
                                     (__attribute__((address_space(3))) void*)l, 16, 0, 0);
}

// ---------------- embedding + ln1(layer0) ----------------
__global__ __launch_bounds__(256) void k_embln(const int* __restrict__ tok,
        const float* __restrict__ emb, const float* __restrict__ pe,
        const float* __restrict__ g, const float* __restrict__ b,
        float* __restrict__ x, u16* __restrict__ out) {
    int row = blockIdx.x, tid = threadIdx.x;
    int t = row & (T - 1);
    int vv = tok[row];
    f32x4 v = ((const f32x4*)(emb + (size_t)vv * D))[tid] + ((const f32x4*)(pe + (size_t)t * D))[tid];
    ((f32x4*)(x + (size_t)row * D))[tid] = v;
    float s = v[0] + v[1] + v[2] + v[3];
    float s2 = v[0]*v[0] + v[1]*v[1] + v[2]*v[2] + v[3]*v[3];
#pragma unroll
    for (int m = 1; m < 64; m <<= 1) { s += __shfl_xor(s, m); s2 += __shfl_xor(s2, m); }
    __shared__ float ps[4], ps2[4];
    int wave = tid >> 6;
    if ((tid & 63) == 0) { ps[wave] = s; ps2[wave] = s2; }
    __syncthreads();
    s = ps[0] + ps[1] + ps[2] + ps[3];
    s2 = ps2[0] + ps2[1] + ps2[2] + ps2[3];
    float mean = s * (1.f / D);
    float var = s2 * (1.f / D) - mean * mean;
    float r = rsqrtf(var + 1e-5f);
    f32x4 gg = ((const f32x4*)g)[tid];
    f32x4 bb = ((const f32x4*)b)[tid];
    u16x4 o;
#pragma unroll
    for (int j = 0; j < 4; j++) o[j] = f2bf((v[j] - mean) * r * gg[j] + bb[j]);
    ((u16x4*)(out + (size_t)row * D))[tid] = o;
}

// ---------------- splitK reduce + bias + residual + LayerNorm ----------------
template <int S>
__global__ __launch_bounds__(256) void k_redln(const float* __restrict__ pp,
        const float* __restrict__ bias, float* __restrict__ x,
        const float* __restrict__ g, const float* __restrict__ b,
        u16* __restrict__ out) {
    int row = blockIdx.x, tid = threadIdx.x;
    f32x4 v = ((const f32x4*)(x + (size_t)row * D))[tid];
#pragma unroll
    for (int s = 0; s < S; s++)
        v += ((const f32x4*)(pp + ((size_t)s * (B * T) + row) * D))[tid];
    v += ((const f32x4*)bias)[tid];
    ((f32x4*)(x + (size_t)row * D))[tid] = v;
    float s = v[0] + v[1] + v[2] + v[3];
    float s2 = v[0]*v[0] + v[1]*v[1] + v[2]*v[2] + v[3]*v[3];
#pragma unroll
    for (int m = 1; m < 64; m <<= 1) { s += __shfl_xor(s, m); s2 += __shfl_xor(s2, m); }
    __shared__ float ps[4], ps2[4];
    int wave = tid >> 6;
    if ((tid & 63) == 0) { ps[wave] = s; ps2[wave] = s2; }
    __syncthreads();
    s = ps[0] + ps[1] + ps[2] + ps[3];
    s2 = ps2[0] + ps2[1] + ps2[2] + ps2[3];
    float mean = s * (1.f / D);
    float var = s2 * (1.f / D) - mean * mean;
    float r = rsqrtf(var + 1e-5f);
    f32x4 gg = ((const f32x4*)g)[tid];
    f32x4 bb = ((const f32x4*)b)[tid];
    u16x4 o;
#pragma unroll
    for (int j = 0; j < 4; j++) o[j] = f2bf((v[j] - mean) * r * gg[j] + bb[j]);
    ((u16x4*)(out + (size_t)row * D))[tid] = o;
}

// ---------------- elementwise cast f32 -> bf16 ----------------
__global__ __launch_bounds__(256) void k_cast(const float* __restrict__ src,
        u16* __restrict__ dst) {
    int i = (blockIdx.x * 256 + threadIdx.x) * 4;
    f32x4 v = *(const f32x4*)(src + i);
    u16x4 o;
#pragma unroll
    for (int j = 0; j < 4; j++) o[j] = f2bf(v[j]);
    *(u16x4*)(dst + i) = o;
}

// ---------------- batched transpose+cast of one layer's 4 weights ----------------
__global__ __launch_bounds__(256) void k_castT4(const float* __restrict__ Wqkv,
        const float* __restrict__ Wproj, const float* __restrict__ W1,
        const float* __restrict__ W2, u16* __restrict__ wt) {
    int bid = blockIdx.x;
    const float* src; u16* dst; int Rr, Cc, t;
    if (bid < 3072)      { src = Wqkv;  dst = wt;                   Rr = D; Cc = 3 * D; t = bid; }
    else if (bid < 4096) { src = Wproj; dst = wt + 3 * D * D;       Rr = D; Cc = D;     t = bid - 3072; }
    else if (bid < 8192) { src = W1;    dst = wt + 4 * D * D;       Rr = D; Cc = F;     t = bid - 4096; }
    else                 { src = W2;    dst = wt + 4 * D * D + D * F; Rr = F; Cc = D;   t = bid - 8192; }
    int ntx = Cc >> 5;
    int c0 = (t % ntx) * 32, r0 = (t / ntx) * 32;
    __shared__ u16 tl[32][33];
    int x = threadIdx.x & 31, y = threadIdx.x >> 5;
#pragma unroll
    for (int i = 0; i < 4; i++)
        tl[y + i * 8][x] = f2bf(src[(size_t)(r0 + y + i * 8) * Cc + c0 + x]);
    __syncthreads();
#pragma unroll
    for (int i = 0; i < 4; i++)
        dst[(size_t)(c0 + y + i * 8) * Rr + r0 + x] = tl[x][y + i * 8];
}

// ---- shared pipeline helpers (swizzle is a size-independent involution) ----
DEV bf16x8 ldf(const u16* half, int row, int lhi) {
    int lb = row * 64 + lhi * 16;
    lb ^= ((lb >> 9) & 1) << 5;
    return *(const bf16x8*)((const char*)half + lb);
}
DEV void stg(const u16* gb, int ld, int kc, u16* dstBase, int wave, int lane) {
#pragma unroll
    for (int i = 0; i < 2; i++) {
        int p = (wave * 2 + i) * 64 + lane;
        int l = p ^ (((p >> 5) & 1) << 1);
        gl16(gb + (size_t)(l >> 2) * ld + kc + (l & 3) * 8, dstBase + (wave * 2 + i) * 512);
    }
}
#define SB_BAR() do { __builtin_amdgcn_sched_barrier(0); __builtin_amdgcn_s_barrier(); } while (0)

// ---------------- 128x128 BK=64 counted-vmcnt pipelined GEMM (4 waves) ----------------
// Same 4-phase schedule/ledger as k_gemm8, shrunk to 128-row halves. LDS 64 KiB -> 2 blk/CU.
// EPI: 0 = bf16 store (VT: V cols -> vT), 1 = GELU->bf16, 4 = f32 splitK partial.
template <int EPI, bool VT>
__global__ __launch_bounds__(256, 2) void k_gemm4(
        const u16* __restrict__ A, int lda,
        const u16* __restrict__ Bt, int ldb,
        const float* __restrict__ bias,
        void* __restrict__ Cv, int ldc, int K, u16* __restrict__ vT) {
    __shared__ u16 lds[2][4][128 * 32];
    int gm = gridDim.x, nwg = gm * gridDim.y;
    int orig = blockIdx.y * gm + blockIdx.x;
    int xcd = orig & 7, idx = orig >> 3;
    int q = nwg >> 3, rr = nwg & 7;
    int wg = (xcd < rr ? xcd * (q + 1) : rr * (q + 1) + (xcd - rr) * q) + idx;
    int m0 = (wg % gm) * 128, n0 = (wg / gm) * 128;
    int koff = (EPI == 4) ? blockIdx.z * K : 0;
    int tid = threadIdx.x, wave = tid >> 6, lane = tid & 63;
    int llo = lane & 15, lhi = lane >> 4;
    int wm = wave >> 1, wn = wave & 1;
    const u16* Ab = A + (size_t)m0 * lda;
    const u16* Bb = Bt + (size_t)n0 * ldb;
    int nk = K >> 6;
    f32x4 acc[4][4] = {};
    // prologue: KT0 all 4 halves, KT1 first 3 (identical ledger to k_gemm8)
    stg(Ab, lda, koff + 0,   &lds[0][0][0], wave, lane);
    stg(Bb, ldb, koff + 0,   &lds[0][1][0], wave, lane);
    stg(Ab, lda, koff + 32,  &lds[0][2][0], wave, lane);
    stg(Bb, ldb, koff + 32,  &lds[0][3][0], wave, lane);
    stg(Ab, lda, koff + 64,  &lds[1][0][0], wave, lane);
    stg(Bb, ldb, koff + 64,  &lds[1][1][0], wave, lane);
    stg(Ab, lda, koff + 96,  &lds[1][2][0], wave, lane);
    asm volatile("s_waitcnt vmcnt(10)");
    SB_BAR();
    for (int t = 0; t < nk; ++t) {
        const int bf = t & 1;
        bf16x8 af[4], b0, b1;
        // ---- phase 1: ks0, ni0-1; stage Bk1(t+1) ----
#pragma unroll
        for (int mi = 0; mi < 4; mi++) af[mi] = ldf(&lds[bf][0][0], wm * 64 + mi * 16 + llo, lhi);
        b0 = ldf(&lds[bf][1][0], wn * 64 + llo, lhi);
        b1 = ldf(&lds[bf][1][0], wn * 64 + 16 + llo, lhi);
        if (t + 1 < nk) stg(Bb, ldb, koff + (t + 1) * 64 + 32, &lds[bf ^ 1][3][0], wave, lane);
        __builtin_amdgcn_s_setprio(1);
#pragma unroll
        for (int mi = 0; mi < 4; mi++) {
            acc[mi][0] = __builtin_amdgcn_mfma_f32_16x16x32_bf16(af[mi], b0, acc[mi][0], 0, 0, 0);
            acc[mi][1] = __builtin_amdgcn_mfma_f32_16x16x32_bf16(af[mi], b1, acc[mi][1], 0, 0, 0);
        }
        __builtin_amdgcn_s_setprio(0);
        SB_BAR();
        // ---- phase 2: ks0, ni2-3; stage Ak0(t+2); vmcnt gate for ph3 ----
        b0 = ldf(&lds[bf][1][0], wn * 64 + 32 + llo, lhi);
        b1 = ldf(&lds[bf][1][0], wn * 64 + 48 + llo, lhi);
        if (t + 2 < nk) stg(Ab, lda, koff + (t + 2) * 64, &lds[bf][0][0], wave, lane);
        __builtin_amdgcn_s_setprio(1);
#pragma unroll
        for (int mi = 0; mi < 4; mi++) {
            acc[mi][2] = __builtin_amdgcn_mfma_f32_16x16x32_bf16(af[mi], b0, acc[mi][2], 0, 0, 0);
            acc[mi][3] = __builtin_amdgcn_mfma_f32_16x16x32_bf16(af[mi], b1, acc[mi][3], 0, 0, 0);
        }
        __builtin_amdgcn_s_setprio(0);
        if (t + 2 < nk)      { asm volatile("s_waitcnt vmcnt(10)"); }
        else if (t + 1 < nk) { asm volatile("s_waitcnt vmcnt(8)"); }
        else                 { asm volatile("s_waitcnt vmcnt(0)"); }
        SB_BAR();
        // ---- phase 3: ks1, ni0-1; stage Bk0(t+2) ----
#pragma unroll
        for (int mi = 0; mi < 4; mi++) af[mi] = ldf(&lds[bf][2][0], wm * 64 + mi * 16 + llo, lhi);
        b0 = ldf(&lds[bf][3][0], wn * 64 + llo, lhi);
        b1 = ldf(&lds[bf][3][0], wn * 64 + 16 + llo, lhi);
        if (t + 2 < nk) stg(Bb, ldb, koff + (t + 2) * 64, &lds[bf][1][0], wave, lane);
        __builtin_amdgcn_s_setprio(1);
#pragma unroll
        for (int mi = 0; mi < 4; mi++) {
            acc[mi][0] = __builtin_amdgcn_mfma_f32_16x16x32_bf16(af[mi], b0, acc[mi][0], 0, 0, 0);
            acc[mi][1] = __builtin_amdgcn_mfma_f32_16x16x32_bf16(af[mi], b1, acc[mi][1], 0, 0, 0);
        }
        __builtin_amdgcn_s_setprio(0);
        SB_BAR();
        // ---- phase 4: ks1, ni2-3; stage Ak1(t+2); vmcnt gate for next ph1 ----
        b0 = ldf(&lds[bf][3][0], wn * 64 + 32 + llo, lhi);
        b1 = ldf(&lds[bf][3][0], wn * 64 + 48 + llo, lhi);
        if (t + 2 < nk) stg(Ab, lda, koff + (t + 2) * 64 + 32, &lds[bf][2][0], wave, lane);
        __builtin_amdgcn_s_setprio(1);
#pragma unroll
        for (int mi = 0; mi < 4; mi++) {
            acc[mi][2] = __builtin_amdgcn_mfma_f32_16x16x32_bf16(af[mi], b0, acc[mi][2], 0, 0, 0);
            acc[mi][3] = __builtin_amdgcn_mfma_f32_16x16x32_bf16(af[mi], b1, acc[mi][3], 0, 0, 0);
        }
        __builtin_amdgcn_s_setprio(0);
        if (t + 1 < nk) {
            if (t + 2 < nk) { asm volatile("s_waitcnt vmcnt(10)"); }
            else            { asm volatile("s_waitcnt vmcnt(4)"); }
        }
        SB_BAR();
    }
#pragma unroll
    for (int ni = 0; ni < 4; ni++) {
        int col = n0 + wn * 64 + ni * 16 + llo;
        float bb = 0.f;
        if (EPI != 4) bb = bias[col];
#pragma unroll
        for (int mi = 0; mi < 4; mi++) {
            int row0 = m0 + wm * 64 + mi * 16 + lhi * 4;
            if (VT && col >= 2 * D) {
                int dv = col - 2 * D;
                int b_ = row0 >> 10, t_ = row0 & (T - 1);
                u16x4 pk;
#pragma unroll
                for (int r = 0; r < 4; r++) pk[r] = f2bf(acc[mi][ni][r] + bb);
                *(u16x4*)(vT + ((size_t)(b_ * 16 + (dv >> 6)) * HD + (dv & 63)) * T + t_) = pk;
            } else {
#pragma unroll
                for (int r = 0; r < 4; r++) {
                    int row = row0 + r;
                    float o = acc[mi][ni][r] + bb;
                    if (EPI == 1) o = 0.5f * o * (1.f + erff(o * 0.70710678118f));
                    if (EPI == 4) {
                        ((float*)Cv)[((size_t)blockIdx.z * (B * T) + row) * ldc + col] = o;
                    } else {
                        ((u16*)Cv)[(size_t)row * ldc + col] = f2bf(o);
                    }
                }
            }
        }
    }
}

// ---------------- 256x256 BK=64 counted-vmcnt pipelined GEMM (8 waves, logits) --------
__global__ __launch_bounds__(512, 2) void k_gemm8(
        const u16* __restrict__ A, int lda,
        const u16* __restrict__ Bt, int ldb,
        const float* __restrict__ bias,
        float* __restrict__ C, int ldc, int K) {
    __shared__ u16 lds[2][4][256 * 32];
    int gm = gridDim.x, nwg = gm * gridDim.y;
    int orig = blockIdx.y * gm + blockIdx.x;
    int xcd = orig & 7, idx = orig >> 3;
    int q = nwg >> 3, rr = nwg & 7;
    int wg = (xcd < rr ? xcd * (q + 1) : rr * (q + 1) + (xcd - rr) * q) + idx;
    int m0 = (wg % gm) * 256, n0 = (wg / gm) * 256;
    int tid = threadIdx.x, wave = tid >> 6, lane = tid & 63;
    int llo = lane & 15, lhi = lane >> 4;
    int wm = wave >> 2, wn = wave & 3;
    const u16* Ab = A + (size_t)m0 * lda;
    const u16* Bb = Bt + (size_t)n0 * ldb;
    int nk = K >> 6;
    f32x4 acc[8][4] = {};
    stg(Ab, lda, 0,   &lds[0][0][0], wave, lane);
    stg(Bb, ldb, 0,   &lds[0][1][0], wave, lane);
    stg(Ab, lda, 32,  &lds[0][2][0], wave, lane);
    stg(Bb, ldb, 32,  &lds[0][3][0], wave, lane);
    stg(Ab, lda, 64,  &lds[1][0][0], wave, lane);
    stg(Bb, ldb, 64,  &lds[1][1][0], wave, lane);
    stg(Ab, lda, 96,  &lds[1][2][0], wave, lane);
    asm volatile("s_waitcnt vmcnt(10)");
    SB_BAR();
    for (int t = 0; t < nk; ++t) {
        const int bf = t & 1;
        bf16x8 af[8], b0, b1;
#pragma unroll
        for (int mi = 0; mi < 8; mi++) af[mi] = ldf(&lds[bf][0][0], wm * 128 + mi * 16 + llo, lhi);
        b0 = ldf(&lds[bf][1][0], wn * 64 + llo, lhi);
        b1 = ldf(&lds[bf][1][0], wn * 64 + 16 + llo, lhi);
        if (t + 1 < nk) stg(Bb, ldb, (t + 1) * 64 + 32, &lds[bf ^ 1][3][0], wave, lane);
        __builtin_amdgcn_s_setprio(1);
#pragma unroll
        for (int mi = 0; mi < 8; mi++) {
            acc[mi][0] = __builtin_amdgcn_mfma_f32_16x16x32_bf16(af[mi], b0, acc[mi][0], 0, 0, 0);
            acc[mi][1] = __builtin_amdgcn_mfma_f32_16x16x32_bf16(af[mi], b1, acc[mi][1], 0, 0, 0);
        }
        __builtin_amdgcn_s_setprio(0);
        SB_BAR();
        b0 = ldf(&lds[bf][1][0], wn * 64 + 32 + llo, lhi);
        b1 = ldf(&lds[bf][1][0], wn * 64 + 48 + llo, lhi);
        if (t + 2 < nk) stg(Ab, lda, (t + 2) * 64, &lds[bf][0][0], wave, lane);
        __builtin_amdgcn_s_setprio(1);
#pragma unroll
        for (int mi = 0; mi < 8; mi++) {
            acc[mi][2] = __builtin_amdgcn_mfma_f32_16x16x32_bf16(af[mi], b0, acc[mi][2], 0, 0, 0);
            acc[mi][3] = __builtin_amdgcn_mfma_f32_16x16x32_bf16(af[mi], b1, acc[mi][3], 0, 0, 0);
        }
        __builtin_amdgcn_s_setprio(0);
        if (t + 2 < nk)      { asm volatile("s_waitcnt vmcnt(10)"); }
        else if (t + 1 < nk) { asm volatile("s_waitcnt vmcnt(8)"); }
        else                 { asm volatile("s_waitcnt vmcnt(0)"); }
        SB_BAR();
#pragma unroll
        for (int mi = 0; mi < 8; mi++) af[mi] = ldf(&lds[bf][2][0], wm * 128 + mi * 16 + llo, lhi);
        b0 = ldf(&lds[bf][3][0], wn * 64 + llo, lhi);
        b1 = ldf(&lds[bf][3][0], wn * 64 + 16 + llo, lhi);
        if (t + 2 < nk) stg(Bb, ldb, (t + 2) * 64, &lds[bf][1][0], wave, lane);
        __builtin_amdgcn_s_setprio(1);
#pragma unroll
        for (int mi = 0; mi < 8; mi++) {
            acc[mi][0] = __builtin_amdgcn_mfma_f32_16x16x32_bf16(af[mi], b0, acc[mi][0], 0, 0, 0);
            acc[mi][1] = __builtin_amdgcn_mfma_f32_16x16x32_bf16(af[mi], b1, acc[mi][1], 0, 0, 0);
        }
        __builtin_amdgcn_s_setprio(0);
        SB_BAR();
        b0 = ldf(&lds[bf][3][0], wn * 64 + 32 + llo, lhi);
        b1 = ldf(&lds[bf][3][0], wn * 64 + 48 + llo, lhi);
        if (t + 2 < nk) stg(Ab, lda, (t + 2) * 64 + 32, &lds[bf][2][0], wave, lane);
        __builtin_amdgcn_s_setprio(1);
#pragma unroll
        for (int mi = 0; mi < 8; mi++) {
            acc[mi][2] = __builtin_amdgcn_mfma_f32_16x16x32_bf16(af[mi], b0, acc[mi][2], 0, 0, 0);
            acc[mi][3] = __builtin_amdgcn_mfma_f32_16x16x32_bf16(af[mi], b1, acc[mi][3], 0, 0, 0);
        }
        __builtin_amdgcn_s_setprio(0);
        if (t + 1 < nk) {
            if (t + 2 < nk) { asm volatile("s_waitcnt vmcnt(10)"); }
            else            { asm volatile("s_waitcnt vmcnt(4)"); }
        }
        SB_BAR();
    }
#pragma unroll
    for (int ni = 0; ni < 4; ni++) {
        int col = n0 + wn * 64 + ni * 16 + llo;
        float bb = bias[col];
#pragma unroll
        for (int mi = 0; mi < 8; mi++) {
            int row0 = m0 + wm * 128 + mi * 16 + lhi * 4;
#pragma unroll
            for (int r = 0; r < 4; r++)
                C[(size_t)(row0 + r) * ldc + col] = acc[mi][ni][r] + bb;
        }
    }
}

// ---------------- fused flash attention (+ optional f32 prob write) ----------------
template <int PW>
__global__ __launch_bounds__(256) void k_fattn(const u16* __restrict__ qkv,
        const u16* __restrict__ vT, u16* __restrict__ out, float* __restrict__ attnF) {
    __shared__ u16 plds[4][16 * 40];
    int bh = blockIdx.y; int b = bh >> 4, h = bh & 15;
    int tid = threadIdx.x, wave = tid >> 6, lane = tid & 63;
    int llo = lane & 15, lhi = lane >> 4;
    int i0 = blockIdx.x * 64 + wave * 16;
    const u16* qb = qkv + (size_t)b * T * (3 * D) + h * HD;
    const u16* kb = qb + D;
    const u16* vt = vT + (size_t)bh * HD * T;
    bf16x8 q0 = ld8(qb + (size_t)(i0 + llo) * (3 * D) + lhi * 8);
    bf16x8 q1 = ld8(qb + (size_t)(i0 + llo) * (3 * D) + 32 + lhi * 8);
    int qrow = i0 + llo;
    float m = -3e38f, s = 0.f;
    f32x4 oacc[4] = {};
    u16* pw = &plds[wave][0];
    for (int k0 = 0; k0 < i0 + 16; k0 += 32) {
        f32x4 sc0 = {}, sc1 = {};
        {
            bf16x8 kf0 = ld8(kb + (size_t)(k0 + llo) * (3 * D) + lhi * 8);
            bf16x8 kf1 = ld8(kb + (size_t)(k0 + llo) * (3 * D) + 32 + lhi * 8);
            sc0 = __builtin_amdgcn_mfma_f32_16x16x32_bf16(kf0, q0, sc0, 0, 0, 0);
            sc0 = __builtin_amdgcn_mfma_f32_16x16x32_bf16(kf1, q1, sc0, 0, 0, 0);
        }
        if (k0 + 16 < i0 + 16) {
            bf16x8 kf0 = ld8(kb + (size_t)(k0 + 16 + llo) * (3 * D) + lhi * 8);
            bf16x8 kf1 = ld8(kb + (size_t)(k0 + 16 + llo) * (3 * D) + 32 + lhi * 8);
            sc1 = __builtin_amdgcn_mfma_f32_16x16x32_bf16(kf0, q0, sc1, 0, 0, 0);
            sc1 = __builtin_amdgcn_mfma_f32_16x16x32_bf16(kf1, q1, sc1, 0, 0, 0);
        }
        float vv[8]; float mx = m;
#pragma unroll
        for (int hf = 0; hf < 2; hf++)
#pragma unroll
            for (int r = 0; r < 4; r++) {
                int k = k0 + hf * 16 + lhi * 4 + r;
                float x = (hf ? sc1[r] : sc0[r]) * 0.125f;
                float v = (k <= qrow) ? x : -3e38f;
                vv[hf * 4 + r] = v;
                mx = fmaxf(mx, v);
            }
        mx = fmaxf(mx, __shfl_xor(mx, 16));
        mx = fmaxf(mx, __shfl_xor(mx, 32));
        float p[8]; float ps = 0.f;
#pragma unroll
        for (int j = 0; j < 8; j++) { p[j] = __expf(vv[j] - mx); ps += p[j]; }
        ps += __shfl_xor(ps, 16);
        ps += __shfl_xor(ps, 32);
        float scale = __expf(m - mx);
        s = s * scale + ps;
        m = mx;
        float sr[4];
#pragma unroll
        for (int r = 0; r < 4; r++) sr[r] = __shfl(scale, lhi * 4 + r);
#pragma unroll
        for (int n = 0; n < 4; n++)
#pragma unroll
            for (int r = 0; r < 4; r++) oacc[n][r] *= sr[r];
#pragma unroll
        for (int hf = 0; hf < 2; hf++) {
            u16x4 pk;
#pragma unroll
            for (int r = 0; r < 4; r++) pk[r] = f2bf(p[hf * 4 + r]);
            *(u16x4*)(pw + llo * 40 + hf * 16 + lhi * 4) = pk;
        }
        bf16x8 pa = ld8(pw + llo * 40 + lhi * 8);
#pragma unroll
        for (int n = 0; n < 4; n++) {
            bf16x8 vb = ld8(vt + (size_t)(n * 16 + llo) * T + k0 + lhi * 8);
            oacc[n] = __builtin_amdgcn_mfma_f32_16x16x32_bf16(pa, vb, oacc[n], 0, 0, 0);
        }
    }
    float inv = 1.f / s;
    float ir[4];
#pragma unroll
    for (int r = 0; r < 4; r++) ir[r] = __shfl(inv, lhi * 4 + r);
#pragma unroll
    for (int n = 0; n < 4; n++)
#pragma unroll
        for (int r = 0; r < 4; r++) {
            int i = i0 + lhi * 4 + r, c = n * 16 + llo;
            out[(size_t)(b * T + i) * D + h * HD + c] = f2bf(oacc[n][r] * ir[r]);
        }
    if (PW) {
        float* ar = attnF + ((size_t)bh * T + qrow) * T;
        for (int j0 = 0; j0 < T; j0 += 16) {
            f32x4 pv = {};
            if (j0 <= qrow) {
                if (j0 < i0 + 16) {
                    bf16x8 kf0 = ld8(kb + (size_t)(j0 + llo) * (3 * D) + lhi * 8);
                    bf16x8 kf1 = ld8(kb + (size_t)(j0 + llo) * (3 * D) + 32 + lhi * 8);
                    f32x4 sc = {};
                    sc = __builtin_amdgcn_mfma_f32_16x16x32_bf16(kf0, q0, sc, 0, 0, 0);
                    sc = __builtin_amdgcn_mfma_f32_16x16x32_bf16(kf1, q1, sc, 0, 0, 0);
#pragma unroll
                    for (int r = 0; r < 4; r++) {
                        int j = j0 + lhi * 4 + r;
                        pv[r] = (j <= qrow) ? __expf(sc[r] * 0.125f - m) * inv : 0.f;
                    }
                }
            }
            *(f32x4*)(ar + j0 + lhi * 4) = pv;
        }
    }
}

extern "C" void kernel_launch(void* const* d_in, const int* in_sizes, int n_in,
                              void* d_out, int out_size, void* d_ws, size_t ws_size,
                              hipStream_t stream) {
    const int*   tok   = (const int*)d_in[0];
    const float* emb   = (const float*)d_in[2];
    const float* pe    = (const float*)d_in[3];
    const float* ln1g  = (const float*)d_in[4];
    const float* ln1b  = (const float*)d_in[5];
    const float* Wqkv  = (const float*)d_in[6];
    const float* bqkv  = (const float*)d_in[7];
    const float* Wproj = (const float*)d_in[8];
    const float* bproj = (const float*)d_in[9];
    const float* ln2g  = (const float*)d_in[10];
    const float* ln2b  = (const float*)d_in[11];
    const float* W1    = (const float*)d_in[12];
    const float* b1    = (const float*)d_in[13];
    const float* W2    = (const float*)d_in[14];
    const float* b2    = (const float*)d_in[15];
    const float* lnfg  = (const float*)d_in[16];
    const float* lnfb  = (const float*)d_in[17];
    const float* outb  = (const float*)d_in[18];

    float* logits  = (float*)d_out;
    float* attnF   = logits + (size_t)B * T * V;

    char* w = (char*)d_ws;
    float* x    = (float*)w;  w += (size_t)B * T * D * 4;
    u16* lnout  = (u16*)w;    w += (size_t)B * T * D * 2;
    u16* qkv    = (u16*)w;    w += (size_t)B * T * 3 * D * 2;
    u16* vT     = (u16*)w;    w += (size_t)B * H * HD * T * 2;
    u16* aout   = (u16*)w;    w += (size_t)B * T * D * 2;
    char* tail = w;
    u16* hmid   = (u16*)w;    w += (size_t)B * T * F * 2;
    u16* WTL    = (u16*)w;    w += (size_t)(5 * D * D + 2 * D * F) * 2;
    float* pp   = (float*)w;  w += (size_t)4 * B * T * D * 4;
    u16* embB   = (u16*)tail;

    dim3 blk(256);
    k_embln<<<dim3(B * T), blk, 0, stream>>>(tok, emb, pe, ln1g, ln1b, x, lnout);

    for (int l = 0; l < L; l++) {
        k_castT4<<<dim3(12288), blk, 0, stream>>>(
            Wqkv + (size_t)l * D * 3 * D, Wproj + (size_t)l * D * D,
            W1 + (size_t)l * D * F, W2 + (size_t)l * F * D, WTL);
        k_gemm4<0, true><<<dim3(B * T / 128, 3 * D / 128), blk, 0, stream>>>(
            lnout, D, WTL, D, bqkv + l * 3 * D, qkv, 3 * D, D, vT);
        if (l == L - 1)
            k_fattn<1><<<dim3(T / 64, B * H), blk, 0, stream>>>(qkv, vT, aout, attnF);
        else
            k_fattn<0><<<dim3(T / 64, B * H), blk, 0, stream>>>(qkv, vT, aout, attnF);
        k_gemm4<4, false><<<dim3(B * T / 128, D / 128, 2), blk, 0, stream>>>(
            aout, D, WTL + (size_t)3 * D * D, D, nullptr, pp, D, D / 2, nullptr);
        k_redln<2><<<dim3(B * T), blk, 0, stream>>>(pp, bproj + l * D, x,
            ln2g + l * D, ln2b + l * D, lnout);
        k_gemm4<1, false><<<dim3(B * T / 128, F / 128), blk, 0, stream>>>(
            lnout, D, WTL + (size_t)4 * D * D, D, b1 + l * F, hmid, F, D, nullptr);
        k_gemm4<4, false><<<dim3(B * T / 128, D / 128, 4), blk, 0, stream>>>(
            hmid, F, WTL + (size_t)4 * D * D + D * F, F, nullptr, pp, D, F / 4, nullptr);
        const float* ng = (l == L - 1) ? lnfg : ln1g + (l + 1) * D;
        const float* nb = (l == L - 1) ? lnfb : ln1b + (l + 1) * D;
        k_redln<4><<<dim3(B * T), blk, 0, stream>>>(pp, b2 + l * D, x, ng, nb, lnout);
    }
    k_cast<<<dim3(V * D / 1024), blk, 0, stream>>>(emb, embB);
    k_gemm8<<<dim3(B * T / 256, V / 256), dim3(512), 0, stream>>>(
        lnout, D, embB, D, outb, logits, V, D);
}